// Round 12
// baseline (2927.822 us; speedup 1.0000x reference)
//
#include <hip/hip_runtime.h>
#include <hip/hip_bf16.h>
#include <math.h>

typedef unsigned short u16;
typedef unsigned int u32;
typedef unsigned long long u64;

#define Bc   2
#define NHc  8
#define Sc   5440
#define NQc  300
#define NEc  6
#define NDc  6
#define FFc  1024
#define BSc  (Bc*Sc)        // 10880
#define BNQc (Bc*NQc)       // 600

__device__ __forceinline__ float us2f(u16 u) {
    union { float f; unsigned v; } x; x.v = ((unsigned)u) << 16; return x.f;
}

// bf16 round-to-nearest-even (finite inputs)
__device__ __forceinline__ u16 f2bf(float f) {
    unsigned u = __float_as_uint(f);
    unsigned r = u + 0x7FFFu + ((u >> 16) & 1u);
    return (u16)(r >> 16);
}
__device__ __forceinline__ float bf2f(u16 u) { return us2f(u); }
__device__ __forceinline__ unsigned pk2(u16 a, u16 b) { return (unsigned)a | ((unsigned)b << 16); }

// k-tile-blocked plane layout: 32-k slabs, rows contiguous within a slab.
__device__ __forceinline__ size_t pidx(int row, int k) {
    return (size_t)(k >> 5) * ((size_t)BSc * 32) + ((size_t)row << 5) + (size_t)(k & 31);
}

// bijective XCD chunked swizzle (m204): contiguous ids -> same XCD's L2
__device__ __forceinline__ int xcd_swz(int orig, int nwg) {
    int xcd = orig & 7;
    int q = nwg >> 3, r = nwg & 7;
    int base = (xcd < r) ? xcd * (q + 1) : r * (q + 1) + (xcd - r) * q;
    return base + (orig >> 3);
}

using bf16x8 = __attribute__((ext_vector_type(8))) short;
using f32x4  = __attribute__((ext_vector_type(4))) float;

// ---------------- dtype detection (proven) ----------------
__global__ void k_detect(const u16* __restrict__ src, int* __restrict__ flag) {
    __shared__ int cnt;
    if (threadIdx.x == 0) cnt = 0;
    __syncthreads();
    u16 v = src[threadIdx.x];
    int e = (v >> 7) & 0xFF;
    int plaus = (e == 0) || (e >= 107 && e <= 131);
    atomicAdd(&cnt, plaus);
    __syncthreads();
    if (threadIdx.x == 0) *flag = (cnt >= 224) ? 1 : 0;
}

// ---------------- fused conversion of ALL inputs (8 elems/thread) ------------
// skip: bitmask of segments whose f32 copy is DEAD in fast(bf16) mode.
struct CvtArgs {
    const void* in[48];
    long off[48];
    int n[48];
    int cnt;
    long total;
    u64 skip;
};
__global__ void k_cvt_all8(CvtArgs args, float* __restrict__ out,
                           const int* __restrict__ flag) {
    long g = ((long)blockIdx.x * 256 + threadIdx.x) * 8;
    if (g >= args.total) return;
    int lo = 0, hi = args.cnt - 1;
    while (lo < hi) {
        int mid = (lo + hi + 1) >> 1;
        if (args.off[mid] <= g) lo = mid; else hi = mid - 1;
    }
    long local = g - args.off[lo];
    long n = (long)args.n[lo];
    float v[8];
#pragma unroll
    for (int j = 0; j < 8; ++j) v[j] = 0.f;
    if (*flag) {
        if ((args.skip >> lo) & 1) return;     // f32 copy never read in fast mode
        const u16* p = (const u16*)args.in[lo] + local;
        if (local + 8 <= n) {
            uint4 r = *(const uint4*)p;
            const u16* pu = (const u16*)&r;
#pragma unroll
            for (int j = 0; j < 8; ++j) v[j] = us2f(pu[j]);
        } else {
            for (int j = 0; j < 8; ++j)
                if (local + j < n) v[j] = us2f(p[j]);
        }
    } else {
        const float* p = (const float*)args.in[lo] + local;
        if (local + 8 <= n) {
            float4 a = ((const float4*)p)[0];
            float4 b = ((const float4*)p)[1];
            v[0] = a.x; v[1] = a.y; v[2] = a.z; v[3] = a.w;
            v[4] = b.x; v[5] = b.y; v[6] = b.z; v[7] = b.w;
        } else {
            for (int j = 0; j < 8; ++j)
                if (local + j < n) v[j] = p[j];
        }
    }
    float4 o0, o1;
    o0.x = v[0]; o0.y = v[1]; o0.z = v[2]; o0.w = v[3];
    o1.x = v[4]; o1.y = v[5]; o1.z = v[6]; o1.w = v[7];
    ((float4*)(out + g))[0] = o0;
    ((float4*)(out + g))[1] = o1;
}

// ---------------- fused prologue: enc planes + (enc+pos) planes --------------
__global__ void k_addf2(const float* __restrict__ a, const float* __restrict__ pos,
                        u16* __restrict__ ah, u16* __restrict__ al,
                        u16* __restrict__ ph, u16* __restrict__ pl, int n) {
    int i = blockIdx.x * 256 + threadIdx.x;
    if (i >= n) return;
    int row = i >> 8, k = i & 255;
    size_t px = pidx(row, k);
    float x = a[i];
    u16 h = f2bf(x);
    ah[px] = h;
    al[px] = f2bf(x - bf2f(h));
    float s = x + pos[i];
    u16 h2 = f2bf(s);
    ph[px] = h2;
    pl[px] = f2bf(s - bf2f(h2));
}

// ---------------- MFMA GEMM, blocked-plane-A, 8-wave split-K -----------------
// C[ldc] = (Ah+Al)[BSc,K](bf16 planes, pidx layout) * W[K,N](ldw) + bias.
// M = BSc, N%128==0, K%64==0 (callers: 256, 1024).
// 512 threads: waves 0-3 accumulate K-half 0, waves 4-7 K-half 1 (own LDS
// buffers) -> 2x in-flight memory per CU per step, half the trip count.
// Final cross-half combine through LDS scratch; epilogue by half 0.
// blockIdx.z batches independent weight slices (decoder V-projections).
template<int RELU>
__global__ __launch_bounds__(512) void k_mgemm(
    const u16* __restrict__ Ah, const u16* __restrict__ Al,
    const float* __restrict__ W, const u16* __restrict__ Wraw, int ldw,
    size_t wstride,
    const float* __restrict__ bias, int bstride,
    float* __restrict__ C, size_t cstride,
    u16* __restrict__ Ch, u16* __restrict__ Cl,
    int ldc, int K,
    const int* __restrict__ flag) {
    __shared__ __align__(16) u16 lds16[32768];   // 64KB: [AH0 AH1 AL0 AL1 BH0 BH1 BL0 BL1]
    const int t = threadIdx.x;
    int lin = blockIdx.x + gridDim.x * blockIdx.y;
    lin = xcd_swz(lin, gridDim.x * gridDim.y);
    const int row0 = (lin / gridDim.x) * 128, col0 = (lin % gridDim.x) * 128;
    const int z = blockIdx.z;
    const int fast = *flag;
    const size_t PSLAB = (size_t)BSc * 32;
    W += (size_t)z * wstride;
    Wraw += (size_t)z * wstride;
    C += (size_t)z * cstride;
    bias += (size_t)z * bstride;

    const int w = t >> 6, lane = t & 63;
    const int kh = w >> 2, wl = w & 3;           // K-half, wave-in-half
    const int th = t & 255;                      // staging role within half
    const int K2 = K >> 1;
    const int nslab = K2 >> 5;
    const size_t baseOff = (size_t)(kh * nslab) * PSLAB;

    // per-half LDS regions (u16 offsets)
    u16* LAH = lds16 + (kh << 12);
    u16* LAL = lds16 + 8192 + (kh << 12);
    u16* LBH = lds16 + 16384 + (kh << 12);
    u16* LBL = lds16 + 24576 + (kh << 12);

    // A staging: chunk c (0..511) of the contiguous 8KB slab tile.
    const int c0 = th, c1 = 256 + th;
    const size_t abase = (size_t)row0 * 32;
    const u16* a0h = Ah + abase + (size_t)c0 * 8 + baseOff;
    const u16* a1h = Ah + abase + (size_t)c1 * 8 + baseOff;
    const u16* a0l = Al + abase + (size_t)c0 * 8 + baseOff;
    const u16* a1l = Al + abase + (size_t)c1 * 8 + baseOff;
    const unsigned d0 = (((unsigned)c0 & ~3u) | (((unsigned)c0 & 3u) ^ (((unsigned)c0 >> 3) & 3u))) * 8u;
    const unsigned d1 = (((unsigned)c1 & ~3u) | (((unsigned)c1 & 3u) ^ (((unsigned)c1 >> 3) & 3u))) * 8u;

    // B staging roles: 32k x 128 cols, thread=(k-pair, col-oct); rows offset by half
    const int bkp = th >> 4, bno = th & 15;
    const float* bp = W + (size_t)(kh * K2 + bkp * 2) * ldw + col0 + bno * 8;
    const u16*  brp = Wraw + (size_t)(kh * K2 + bkp * 2) * ldw + col0 + bno * 8;

    const int wr = (wl >> 1) * 64, wc = (wl & 1) * 64;
    const int kg = lane >> 4, lr = lane & 15;

    unsigned iaf[4];
#pragma unroll
    for (int mi = 0; mi < 4; ++mi) {
        int arow = wr + mi * 16 + lr;
        iaf[mi] = ((unsigned)(arow << 2) + ((unsigned)kg ^ (((unsigned)arow >> 1) & 3u))) * 8u;
    }

    f32x4 acc[4][4] = {};
    uint4 aU0h, aU1h, aU0l, aU1l;
    float4 bR[4];
    uint4 bU0, bU1;
    aU0h = *(const uint4*)a0h;
    aU1h = *(const uint4*)a1h;
    aU0l = *(const uint4*)a0l;
    aU1l = *(const uint4*)a1l;
    if (fast) {
        bU0 = *(const uint4*)brp;
        bU1 = *(const uint4*)(brp + ldw);
    } else {
        const float4* q0 = (const float4*)bp;
        const float4* q1 = (const float4*)(bp + ldw);
        bR[0] = q0[0]; bR[1] = q0[1]; bR[2] = q1[0]; bR[3] = q1[1];
    }

    for (int k0 = 0; k0 < K2; k0 += 32) {
        if (k0) __syncthreads();
        // ---- A: 4 vector LDS writes (contiguous per wave, conflict-free) ----
        *(uint4*)&LAH[d0] = aU0h;
        *(uint4*)&LAH[d1] = aU1h;
        *(uint4*)&LAL[d0] = aU0l;
        *(uint4*)&LAL[d1] = aU1l;
        // ---- B: transpose-stage from registers ----
        {
            unsigned bb = (unsigned)(bkp >> 2) * 1024u + (unsigned)(bkp & 3) * 2u;
            if (fast) {
                const u16* e0 = (const u16*)&bU0;
                const u16* e1 = (const u16*)&bU1;
#pragma unroll
                for (int j = 0; j < 8; ++j) {
                    int slot = bno * 8 + (j ^ (bno & 7));   // bank-spread, bijective
                    *(unsigned*)&LBH[bb + (unsigned)slot * 8u] = pk2(e0[j], e1[j]);
                }
            } else {
                float e0f[8], e1f[8];
                *(float4*)&e0f[0] = bR[0]; *(float4*)&e0f[4] = bR[1];
                *(float4*)&e1f[0] = bR[2]; *(float4*)&e1f[4] = bR[3];
#pragma unroll
                for (int j = 0; j < 8; ++j) {
                    int slot = bno * 8 + (j ^ (bno & 7));
                    u16 h0 = f2bf(e0f[j]), h1 = f2bf(e1f[j]);
                    *(unsigned*)&LBH[bb + (unsigned)slot * 8u] = pk2(h0, h1);
                    u16 l0 = f2bf(e0f[j] - bf2f(h0));
                    u16 l1 = f2bf(e1f[j] - bf2f(h1));
                    *(unsigned*)&LBL[bb + (unsigned)slot * 8u] = pk2(l0, l1);
                }
            }
        }
        __syncthreads();
        // prefetch next tile into regs (overlaps fragment reads + MFMA)
        if (k0 + 32 < K2) {
            size_t soff = (size_t)((k0 >> 5) + 1) * PSLAB;
            aU0h = *(const uint4*)(a0h + soff);
            aU1h = *(const uint4*)(a1h + soff);
            aU0l = *(const uint4*)(a0l + soff);
            aU1l = *(const uint4*)(a1l + soff);
            if (fast) {
                bU0 = *(const uint4*)(brp + (size_t)(k0 + 32) * ldw);
                bU1 = *(const uint4*)(brp + (size_t)(k0 + 33) * ldw);
            } else {
                const float4* q0 = (const float4*)(bp + (size_t)(k0 + 32) * ldw);
                const float4* q1 = (const float4*)(bp + (size_t)(k0 + 33) * ldw);
                bR[0] = q0[0]; bR[1] = q0[1]; bR[2] = q1[0]; bR[3] = q1[1];
            }
        }
        // ---- fragments + MFMA ----
        bf16x8 aH[4], aL[4], bH[4], bL[4];
#pragma unroll
        for (int mi = 0; mi < 4; ++mi) {
            aH[mi] = *(const bf16x8*)&LAH[iaf[mi]];
            aL[mi] = *(const bf16x8*)&LAL[iaf[mi]];
        }
#pragma unroll
        for (int ni = 0; ni < 4; ++ni) {
            int c = wc + ni * 16 + lr;
            int slot = (c & ~7) | ((c ^ (c >> 3)) & 7);
            unsigned ib = (unsigned)kg * 1024u + (unsigned)slot * 8u;
            bH[ni] = *(const bf16x8*)&LBH[ib];
            if (!fast) bL[ni] = *(const bf16x8*)&LBL[ib];
        }
#pragma unroll
        for (int mi = 0; mi < 4; ++mi)
#pragma unroll
            for (int ni = 0; ni < 4; ++ni) {
                acc[mi][ni] = __builtin_amdgcn_mfma_f32_16x16x32_bf16(aH[mi], bH[ni], acc[mi][ni], 0, 0, 0);
                acc[mi][ni] = __builtin_amdgcn_mfma_f32_16x16x32_bf16(aL[mi], bH[ni], acc[mi][ni], 0, 0, 0);
            }
        if (!fast) {
#pragma unroll
            for (int mi = 0; mi < 4; ++mi)
#pragma unroll
                for (int ni = 0; ni < 4; ++ni)
                    acc[mi][ni] = __builtin_amdgcn_mfma_f32_16x16x32_bf16(aH[mi], bL[ni], acc[mi][ni], 0, 0, 0);
        }
    }
    // ---- cross-half combine through LDS scratch (64KB = 256 thr x 64 f32) ----
    __syncthreads();
    float* scr = (float*)lds16;
    if (kh == 1) {
        float* s = scr + (size_t)th * 64;
#pragma unroll
        for (int ni = 0; ni < 4; ++ni)
#pragma unroll
            for (int mi = 0; mi < 4; ++mi)
#pragma unroll
                for (int r2 = 0; r2 < 4; ++r2)
                    s[(ni * 4 + mi) * 4 + r2] = acc[mi][ni][r2];
    }
    __syncthreads();
    if (kh == 0) {
        const float* s = scr + (size_t)th * 64;
        const int rb = row0 + wr + (lane >> 4) * 4;
#pragma unroll
        for (int ni = 0; ni < 4; ++ni) {
            int cc = col0 + wc + ni * 16 + lr;
            float bv = bias[cc];
#pragma unroll
            for (int mi = 0; mi < 4; ++mi) {
#pragma unroll
                for (int r2 = 0; r2 < 4; ++r2) {
                    int rr = rb + mi * 16 + r2;
                    float v = acc[mi][ni][r2] + s[(ni * 4 + mi) * 4 + r2] + bv;
                    if (RELU) v = fmaxf(v, 0.f);
                    if (C) C[(size_t)rr * ldc + cc] = v;
                    if (Ch) {
                        size_t px = pidx(rr, cc);
                        u16 h = f2bf(v);
                        Ch[px] = h;
                        Cl[px] = f2bf(v - bf2f(h));
                    }
                }
            }
        }
    }
}

// ---------------- double-buffered small-M GEMM: 64x64 tile, 4x4 micro --------
template<int RELU>
__global__ __launch_bounds__(256) void k_dgemm(
    const float* __restrict__ A, int lda,
    const float* __restrict__ W, int ldw, int wcol0,
    const float* __restrict__ bias,
    float* __restrict__ C, int ldc,
    int M, int N, int K) {
    __shared__ float As[2][16][68];
    __shared__ float Bs[2][16][68];
    int t = threadIdx.x;
    int row0 = blockIdx.y * 64, col0 = blockIdx.x * 64;
    int ti = t >> 4, tj = t & 15;
    int arow = t >> 2, akq = (t & 3) << 2;
    int bk = t >> 4, bn = (t & 15) << 2;
    bool aok = (row0 + arow) < M;
    const float* ap = A + (size_t)(row0 + arow) * lda + akq;
    const float* bp = W + (size_t)bk * ldw + wcol0 + col0 + bn;
    float4 aR = aok ? *(const float4*)ap : make_float4(0.f, 0.f, 0.f, 0.f);
    float4 bR = *(const float4*)bp;
    As[0][akq + 0][arow] = aR.x;
    As[0][akq + 1][arow] = aR.y;
    As[0][akq + 2][arow] = aR.z;
    As[0][akq + 3][arow] = aR.w;
    *(float4*)&Bs[0][bk][bn] = bR;
    __syncthreads();
    int cur = 0;
    float acc[4][4] = {};
    for (int k0 = 0; k0 < K; k0 += 16) {
        bool more = (k0 + 16) < K;
        if (more) {
            aR = aok ? *(const float4*)(ap + k0 + 16) : make_float4(0.f, 0.f, 0.f, 0.f);
            bR = *(const float4*)(bp + (size_t)(k0 + 16) * ldw);
        }
#pragma unroll
        for (int k = 0; k < 16; ++k) {
            float a[4], b[4];
#pragma unroll
            for (int r = 0; r < 4; ++r) a[r] = As[cur][k][ti * 4 + r];
#pragma unroll
            for (int c = 0; c < 4; ++c) b[c] = Bs[cur][k][tj * 4 + c];
#pragma unroll
            for (int r = 0; r < 4; ++r)
#pragma unroll
                for (int c = 0; c < 4; ++c) acc[r][c] += a[r] * b[c];
        }
        if (more) {
            int nxt = cur ^ 1;
            As[nxt][akq + 0][arow] = aR.x;
            As[nxt][akq + 1][arow] = aR.y;
            As[nxt][akq + 2][arow] = aR.z;
            As[nxt][akq + 3][arow] = aR.w;
            *(float4*)&Bs[nxt][bk][bn] = bR;
            __syncthreads();
            cur = nxt;
        }
    }
    for (int r = 0; r < 4; ++r) {
        int rr = row0 + ti * 4 + r;
        if (rr >= M) continue;
        for (int c = 0; c < 4; ++c) {
            int cc = col0 + tj * 4 + c;
            float v = acc[r][c] + bias[cc];
            if (RELU) v = fmaxf(v, 0.f);
            C[(size_t)rr * ldc + cc] = v;
        }
    }
}

// ---------------- bbox-head GEMM (N=4) fused with inverse_sigmoid+sigmoid ----
__global__ __launch_bounds__(256) void k_gemm4(
    const float* __restrict__ A, const float* __restrict__ W,
    const float* __restrict__ bias, const float* __restrict__ rsel,
    float* __restrict__ oref, int M, int K) {
    int row = blockIdx.x * 64 + (threadIdx.x >> 2);
    int col = threadIdx.x & 3;
    if (row >= M) return;
    float acc = 0.f;
    const float* a = A + (size_t)row * K;
    for (int k = 0; k < K; ++k) acc += a[k] * W[k * 4 + col];
    float tmp = acc + bias[col];
    float r = rsel[(size_t)row * 4 + col];
    r = fminf(fmaxf(r, 1e-5f), 1.f - 1e-5f);
    float v = tmp + logf(r / (1.f - r));
    oref[(size_t)row * 4 + col] = 1.f / (1.f + __expf(-v));
}

// ---------------- LayerNorm (residual; optional plane outs; optional store) --
__global__ void k_ln(const float* __restrict__ a, const float* __restrict__ b,
                     const float* __restrict__ g, const float* __restrict__ be,
                     float* __restrict__ o,
                     u16* __restrict__ oh, u16* __restrict__ ol,
                     const float* __restrict__ padd, float* __restrict__ opadd,
                     u16* __restrict__ oph, u16* __restrict__ opl,
                     void* __restrict__ sdst, size_t soff,
                     const int* __restrict__ flag) {
    int row = blockIdx.x;
    int t = threadIdx.x;
    __shared__ float red[256];
    size_t ix = (size_t)row * 256 + t;
    float x = a[ix];
    if (b) x += b[ix];
    red[t] = x;
    __syncthreads();
    for (int s = 128; s > 0; s >>= 1) { if (t < s) red[t] += red[t + s]; __syncthreads(); }
    float mean = red[0] / 256.f;
    __syncthreads();
    float d = x - mean;
    red[t] = d * d;
    __syncthreads();
    for (int s = 128; s > 0; s >>= 1) { if (t < s) red[t] += red[t + s]; __syncthreads(); }
    float var = red[0] / 256.f;
    float y = d * rsqrtf(var + 1e-5f) * g[t] + be[t];
    o[ix] = y;
    if (oh) {
        size_t px = pidx(row, t);
        u16 h = f2bf(y);
        oh[px] = h;
        ol[px] = f2bf(y - bf2f(h));
    }
    if (padd) {
        float z = y + padd[ix];
        if (opadd) opadd[ix] = z;
        if (oph) {
            size_t px = pidx(row, t);
            u16 h = f2bf(z);
            oph[px] = h;
            opl[px] = f2bf(z - bf2f(h));
        }
    }
    if (sdst) {
        if (*flag) ((__hip_bfloat16*)sdst)[soff + ix] = __float2bfloat16(y);
        else       ((float*)sdst)[soff + ix] = y;
    }
}

// ---------------- ref windows ----------------
__global__ void k_refw(float* __restrict__ rw) {
    int s = blockIdx.x * 256 + threadIdx.x;
    if (s >= Sc) return;
    int start, HW;
    if (s < 4096)      { start = 0;    HW = 64; }
    else if (s < 5120) { start = 4096; HW = 32; }
    else if (s < 5376) { start = 5120; HW = 16; }
    else               { start = 5376; HW = 8;  }
    int loc = s - start;
    int i = loc / HW, j = loc % HW;
    rw[s * 4 + 0] = (j + 0.5f) / ((float)HW + 1e-6f);
    rw[s * 4 + 1] = (i + 0.5f) / ((float)HW + 1e-6f);
    rw[s * 4 + 2] = 4.0f / (float)HW;
    rw[s * 4 + 3] = 4.0f / (float)HW;
}

// ---------------- box attention sampling v4: wave/query, float4 channels ------
__global__ __launch_bounds__(256) void k_box_sample4(
    const float* __restrict__ v, const float* __restrict__ attn,
    const float* __restrict__ refw, int ref_bs,
    float* __restrict__ out, u16* __restrict__ outh, u16* __restrict__ outl,
    int N) {
    const int t = threadIdx.x;
    const int qi = t >> 6, lane = t & 63;
    const int blk = xcd_swz(blockIdx.x, gridDim.x);
    const int n = blk * 4 + qi;
    const int b = blockIdx.y;
    if (n >= N) return;                       // wave-uniform
    const float* arow = attn + ((size_t)b * N + n) * 128;
    float2 wl = *(const float2*)(arow + lane * 2);
    float m = fmaxf(wl.x, wl.y);
#pragma unroll
    for (int d2 = 1; d2 < 8; d2 <<= 1) m = fmaxf(m, __shfl_xor(m, d2, 8));
    float e0 = __expf(wl.x - m), e1 = __expf(wl.y - m);
    float s = e0 + e1;
#pragma unroll
    for (int d2 = 1; d2 < 8; d2 <<= 1) s += __shfl_xor(s, d2, 8);
    float inv = 1.f / s;
    e0 *= inv; e1 *= inv;

    const float* rw = refw + (size_t)ref_bs * b + (size_t)n * 4;
    float cx = rw[0], cy = rw[1], bw = rw[2], bh = rw[3];
    const float* vb = v + (size_t)b * Sc * 256 + lane * 4;
    float4 acc = make_float4(0.f, 0.f, 0.f, 0.f);
    int start = 0;
    const int HWs[4] = {64, 32, 16, 8};
#pragma unroll
    for (int l = 0; l < 4; ++l) {
        int HW = HWs[l];
#pragma unroll
        for (int p = 0; p < 4; ++p) {
            float gx = (p & 1) ? 0.25f : -0.25f;
            float gy = (p >> 1) ? 0.25f : -0.25f;
            float x = (cx + gx * bw) * (float)HW - 0.5f;
            float y = (cy + gy * bh) * (float)HW - 0.5f;
            float x0f = floorf(x), y0f = floorf(y);
            float wx = x - x0f, wy = y - y0f;
            int x0 = (int)x0f, y0 = (int)y0f;
            float4 smp = make_float4(0.f, 0.f, 0.f, 0.f);
            if (x0 >= 0 && x0 < HW && y0 >= 0 && y0 < HW) {
                float4 g4 = *(const float4*)(vb + (size_t)(start + y0 * HW + x0) * 256);
                float wgt = (1.f - wx) * (1.f - wy);
                smp.x += wgt * g4.x; smp.y += wgt * g4.y; smp.z += wgt * g4.z; smp.w += wgt * g4.w;
            }
            if (x0 + 1 >= 0 && x0 + 1 < HW && y0 >= 0 && y0 < HW) {
                float4 g4 = *(const float4*)(vb + (size_t)(start + y0 * HW + x0 + 1) * 256);
                float wgt = wx * (1.f - wy);
                smp.x += wgt * g4.x; smp.y += wgt * g4.y; smp.z += wgt * g4.z; smp.w += wgt * g4.w;
            }
            if (x0 >= 0 && x0 < HW && y0 + 1 >= 0 && y0 + 1 < HW) {
                float4 g4 = *(const float4*)(vb + (size_t)(start + (y0 + 1) * HW + x0) * 256);
                float wgt = (1.f - wx) * wy;
                smp.x += wgt * g4.x; smp.y += wgt * g4.y; smp.z += wgt * g4.z; smp.w += wgt * g4.w;
            }
            if (x0 + 1 >= 0 && x0 + 1 < HW && y0 + 1 >= 0 && y0 + 1 < HW) {
                float4 g4 = *(const float4*)(vb + (size_t)(start + (y0 + 1) * HW + x0 + 1) * 256);
                float wgt = wx * wy;
                smp.x += wgt * g4.x; smp.y += wgt * g4.y; smp.z += wgt * g4.z; smp.w += wgt * g4.w;
            }
            const int idx = l * 4 + p;
            float wsel = (idx & 1) ? e1 : e0;
            float wv = __shfl(wsel, (lane & ~7) | (idx >> 1), 64);
            acc.x += wv * smp.x; acc.y += wv * smp.y;
            acc.z += wv * smp.z; acc.w += wv * smp.w;
        }
        start += HW * HW;
    }
    if (out) {
        size_t obase = ((size_t)b * N + n) * 256 + lane * 4;
        *(float4*)(out + obase) = acc;
    }
    if (outh) {
        size_t px = pidx(b * N + n, lane * 4);
        ushort4 h, lo;
        h.x = f2bf(acc.x); h.y = f2bf(acc.y); h.z = f2bf(acc.z); h.w = f2bf(acc.w);
        lo.x = f2bf(acc.x - bf2f(h.x)); lo.y = f2bf(acc.y - bf2f(h.y));
        lo.z = f2bf(acc.z - bf2f(h.z)); lo.w = f2bf(acc.w - bf2f(h.w));
        *(ushort4*)(outh + px) = h;
        *(ushort4*)(outl + px) = lo;
    }
}

// ---------------- cls logits + valid mask ----------------
__global__ void k_cls(const float* __restrict__ x, const float* __restrict__ w,
                      const float* __restrict__ cb, const float* __restrict__ rw,
                      float* __restrict__ logits) {
    int row = blockIdx.x;
    int t = threadIdx.x;
    __shared__ float red[256];
    red[t] = x[(size_t)row * 256 + t] * w[t];
    __syncthreads();
    for (int s = 128; s > 0; s >>= 1) { if (t < s) red[t] += red[t + s]; __syncthreads(); }
    if (t == 0) {
        int s = row % Sc;
        float cx = rw[s * 4], cy = rw[s * 4 + 1];
        bool valid = (cx > 0.01f) && (cx < 0.99f) && (cy > 0.01f) && (cy < 0.99f);
        logits[row] = valid ? (red[0] + cb[0]) : -65504.0f;
    }
}

// ---------------- exact top-k: radix select (parallel suffix scan) + rank emit
__global__ void k_topk(const float* __restrict__ logits, int* __restrict__ idxout) {
    int b = blockIdx.x;
    int t = threadIdx.x;
    __shared__ unsigned keys[Sc];
    __shared__ int hist[256];
    __shared__ int suf[257];
    __shared__ unsigned sprefix;
    __shared__ int sR;
    __shared__ int cnt;
    __shared__ u64 cand[512];
    for (int i = t; i < Sc; i += 256) {
        union { float f; unsigned u; } x;
        x.f = logits[(size_t)b * Sc + i];
        unsigned u = x.u;
        keys[i] = (u & 0x80000000u) ? ~u : (u | 0x80000000u);
    }
    if (t == 0) { sprefix = 0; sR = NQc; suf[256] = 0; }
    __syncthreads();
    for (int shift = 24; shift >= 0; shift -= 8) {
        hist[t] = 0;
        __syncthreads();
        unsigned pref = sprefix;
        int R = sR;
        unsigned pmask = (shift == 24) ? 0u : (0xFFFFFFFFu << (shift + 8));
        for (int i = t; i < Sc; i += 256) {
            unsigned kk = keys[i];
            if ((kk & pmask) == (pref & pmask))
                atomicAdd(&hist[(kk >> shift) & 255], 1);
        }
        __syncthreads();
        suf[t] = hist[t];
        __syncthreads();
        for (int s2 = 1; s2 < 256; s2 <<= 1) {
            int vv = suf[t] + ((t + s2 < 256) ? suf[t + s2] : 0);
            __syncthreads();
            suf[t] = vv;
            __syncthreads();
        }
        if (suf[t] >= R && suf[t + 1] < R) {
            sR = R - suf[t + 1];
            sprefix = pref | ((unsigned)t << shift);
        }
        __syncthreads();
    }
    unsigned T = sprefix;
    if (t == 0) cnt = 0;
    __syncthreads();
    for (int i = t; i < Sc; i += 256) {
        unsigned kk = keys[i];
        if (kk >= T) {
            int slot = atomicAdd(&cnt, 1);
            if (slot < 512)
                cand[slot] = ~((((u64)kk) << 32) | (u64)(0xFFFFFFFFu - (unsigned)i));
        }
    }
    __syncthreads();
    int total = cnt < 512 ? cnt : 512;
    for (int i = t; i < 512; i += 256)
        if (i >= total) cand[i] = 0xFFFFFFFFFFFFFFFFull;
    __syncthreads();
    for (int i = t; i < 512; i += 256) {
        if (i >= total) continue;
        u64 mine = cand[i];
        int rank = 0;
        for (int j = 0; j < 512; ++j) rank += (cand[j] < mine) ? 1 : 0;
        if (rank < NQc) {
            u64 c = ~mine;
            idxout[b * NQc + rank] = (int)(0xFFFFFFFFu - (unsigned)(c & 0xFFFFFFFFull));
        }
    }
}

// ---------------- gather selected rows + ref windows ----------------
__global__ void k_gather(const float* __restrict__ x, const float* __restrict__ rw,
                         const int* __restrict__ idx, float* __restrict__ qemb,
                         float* __restrict__ refsel) {
    int q = blockIdx.x, b = blockIdx.y;
    int t = threadIdx.x;
    int id = idx[b * NQc + q];
    qemb[((size_t)b * NQc + q) * 256 + t] = x[((size_t)b * Sc + id) * 256 + t];
    if (t < 4) refsel[((size_t)b * NQc + q) * 4 + t] = rw[id * 4 + t];
}

// ---------------- sine positional embedding of boxes ----------------
__global__ void k_qpos(const float* __restrict__ outref, float* __restrict__ qpos) {
    int n = blockIdx.x, b = blockIdx.y;
    int t = threadIdx.x;
    const float* orf = outref + ((size_t)b * NQc + n) * 4;
    int c = t >> 7;
    int j = (t & 127) >> 1;
    int si = t & 1;
    float tj = powf(10000.f, (float)j / 64.f);
    float sc = 6.283185307179586f / tj;
    float v1 = orf[c] * sc;
    float v2 = orf[2 + c] * sc;
    float r = si ? (cosf(v1) + cosf(v2)) : (sinf(v1) + sinf(v2));
    qpos[((size_t)b * NQc + n) * 256 + t] = r;
}

// ---------------- MHA v3: thread=(query,head), 10-way key split (300=10x30) --
#define NSPL 10
#define SPLW 30
__global__ __launch_bounds__(256) void k_mha2(
    const float* __restrict__ qk, const float* __restrict__ v,
    float* __restrict__ opart, float* __restrict__ mlpart) {
    __shared__ float lsK[SPLW][256];
    __shared__ float lsV[SPLW][256];
    const int t = threadIdx.x;
    const int h = t >> 5, ql = t & 31;
    const int b = blockIdx.y, z = blockIdx.z;
    const int n = blockIdx.x * 32 + ql;
    const bool qok = n < NQc;
    const int kstart = z * SPLW;
    for (int f = t; f < SPLW * 64; f += 256) {
        int r = f >> 6, c4 = f & 63;
        int krow = kstart + r;
        float4 kv = *(const float4*)(qk + (size_t)(b * NQc + krow) * 512 + 256 + c4 * 4);
        float4 vv = *(const float4*)(v + (size_t)(b * NQc + krow) * 256 + c4 * 4);
        *(float4*)&lsK[r][c4 * 4] = kv;
        *(float4*)&lsV[r][c4 * 4] = vv;
    }
    __syncthreads();
    float q[32];
    {
        const float* qp = qk + (size_t)(b * NQc + (qok ? n : 0)) * 512 + h * 32;
#pragma unroll
        for (int j4 = 0; j4 < 8; ++j4) {
            float4 f = ((const float4*)qp)[j4];
            q[j4 * 4 + 0] = f.x; q[j4 * 4 + 1] = f.y;
            q[j4 * 4 + 2] = f.z; q[j4 * 4 + 3] = f.w;
        }
    }
    const float scale = 0.17677669529663688f;
    float s[SPLW];
#pragma unroll
    for (int kk = 0; kk < SPLW; ++kk) {
        float acc = 0.f;
        const float* kr = &lsK[kk][h * 32];
#pragma unroll
        for (int j4 = 0; j4 < 8; ++j4) {
            float4 kf = ((const float4*)kr)[j4];
            acc += q[j4*4+0]*kf.x + q[j4*4+1]*kf.y + q[j4*4+2]*kf.z + q[j4*4+3]*kf.w;
        }
        s[kk] = acc * scale;
    }
    float m = s[0];
#pragma unroll
    for (int kk = 1; kk < SPLW; ++kk) m = fmaxf(m, s[kk]);
    float o[32];
#pragma unroll
    for (int j = 0; j < 32; ++j) o[j] = 0.f;
    float l = 0.f;
#pragma unroll
    for (int kk = 0; kk < SPLW; ++kk) {
        float e = __expf(s[kk] - m);
        l += e;
        const float* vr = &lsV[kk][h * 32];
#pragma unroll
        for (int j4 = 0; j4 < 8; ++j4) {
            float4 vf = ((const float4*)vr)[j4];
            o[j4*4+0] += e * vf.x; o[j4*4+1] += e * vf.y;
            o[j4*4+2] += e * vf.z; o[j4*4+3] += e * vf.w;
        }
    }
    if (qok) {
        float* op = opart + ((size_t)z * BNQc + (size_t)b * NQc + n) * 256 + h * 32;
#pragma unroll
        for (int j4 = 0; j4 < 8; ++j4) {
            float4 f;
            f.x = o[j4*4+0]; f.y = o[j4*4+1]; f.z = o[j4*4+2]; f.w = o[j4*4+3];
            ((float4*)op)[j4] = f;
        }
        float* mlp = mlpart + ((size_t)z * BNQc + (size_t)b * NQc + n) * 16 + h * 2;
        mlp[0] = m; mlp[1] = l;
    }
}

__global__ void k_mha_comb(const float* __restrict__ opart, const float* __restrict__ mlpart,
                           float* __restrict__ out) {
    int row = blockIdx.x;           // b*NQc + n over BNQc
    int t = threadIdx.x;
    int h = t >> 5;
    float mm[NSPL], ll[NSPL];
    float M = -3.0e38f;
#pragma unroll
    for (int z = 0; z < NSPL; ++z) {
        mm[z] = mlpart[((size_t)z * BNQc + row) * 16 + h * 2];
        ll[z] = mlpart[((size_t)z * BNQc + row) * 16 + h * 2 + 1];
        M = fmaxf(M, mm[z]);
    }
    float denom = 0.f, osum = 0.f;
#pragma unroll
    for (int z = 0; z < NSPL; ++z) {
        float a = __expf(mm[z] - M);
        denom += ll[z] * a;
        osum += opart[((size_t)z * BNQc + row) * 256 + t] * a;
    }
    out[(size_t)row * 256 + t] = osum / denom;
}

// =====================================================================
extern "C" void kernel_launch(void* const* d_in, const int* in_sizes, int n_in,
                              void* d_out, int out_size, void* d_ws, size_t ws_size,
                              hipStream_t stream) {
    char* base = (char*)d_ws;
    size_t off = 0;
    auto allocB = [&](size_t bytes) {
        char* p = base + off;
        off = (off + bytes + 255) & ~(size_t)255;
        return p;
    };
    int* flag = (int*)allocB(16);
    auto allocF = [&](size_t n) { return (float*)allocB(n * 4); };
    auto allocH = [&](size_t n) { return (u16*)allocB(n * 2); };

    k_detect<<<1, 256, 0, stream>>>((const u16*)d_in[0], flag);

    // ---- one fused conversion of all 48 inputs ----
    CvtArgs ca;
    long acc = 0;
    int ninp = n_in < 48 ? n_in : 48;
    for (int i = 0; i < 48; ++i) {
        int idx2 = i < ninp ? i : ninp - 1;
        ca.in[i] = d_in[idx2];
        ca.n[i] = (i < ninp) ? in_sizes[i] : 0;
        ca.off[i] = acc;
        acc += ((long)ca.n[i] + 63) & ~63L;
    }
    ca.cnt = 48;
    ca.total = acc;
    // f32 copies of these segments are dead when inputs are bf16 (mgemm Wraw path)
    ca.skip = (1ull << 2) | (1ull << 4) | (1ull << 6) | (1ull << 8) |
              (1ull << 10) | (1ull << 20);
    float* cvtbase = allocF((size_t)acc);
    k_cvt_all8<<<(int)((acc / 8 + 255) / 256), 256, 0, stream>>>(ca, cvtbase, flag);
    float* F[48];
    for (int i = 0; i < 48; ++i) F[i] = cvtbase + ca.off[i];

    // ---- activation buffers ----
    const size_t BSD = (size_t)BSc * 256;
    float* enc    = F[0];                 // f32 activation (in-place)
    u16* encH  = allocH(BSD);  u16* encL  = allocH(BSD);
    u16* pbufH = allocH(BSD);  u16* pbufL = allocH(BSD);
    u16* tbufH = allocH(BSD);  u16* tbufL = allocH(BSD);
    u16* ffnhH = allocH((size_t)BSc * FFc);
    u16* ffnhL = allocH((size_t)BSc * FFc);
    float* vbuf   = allocF(BSD);               // encoder value buffer
    float* vbuf6  = allocF((size_t)NDc * BSD); // 6 decoder value buffers
    float* gout   = allocF(BSD);
    float* attnb  = allocF((size_t)BSc * 128);
    float* refw   = allocF(Sc * 4);
    float* logit  = allocF(BSc);
    int*   idx    = (int*)allocB(BNQc * 4);
    float* qemb   = allocF((size_t)BNQc * 256);
    float* rsel   = allocF(BNQc * 4);
    float* xbuf   = allocF((size_t)BNQc * 256);
    float* qposb  = allocF((size_t)BNQc * 256);
    float* dqk    = allocF((size_t)BNQc * 256);
    float* dqk512 = allocF((size_t)BNQc * 512);
    float* dv     = allocF((size_t)BNQc * 256);
    float* dt1    = allocF((size_t)BNQc * 256);
    float* dt2    = allocF((size_t)BNQc * 256);
    float* datt   = allocF((size_t)BNQc * 128);
    float* dffnh  = allocF((size_t)BNQc * FFc);
    float* h1f    = allocF((size_t)BNQc * 256);
    float* h2f    = allocF((size_t)BNQc * 256);
    float* oref   = allocF(BNQc * 4);
    float* opart  = allocF((size_t)NSPL * BNQc * 256);
    float* mlpart = allocF((size_t)NSPL * BNQc * 16);
    (void)ws_size; (void)out_size;

    auto MG = [&](int relu, const u16* Ah, const u16* Al, int widx, size_t woff, int ldw,
                  const float* bias, float* Cf, u16* Ch, u16* Cl, int ldc, int N, int K,
                  int nz, size_t wstride, int bstride, size_t cstride) {
        const float* Wf = F[widx] + woff;
        const u16* Wraw = (const u16*)d_in[widx] + woff;
        dim3 g(N / 128, BSc / 128, nz);
        if (relu) k_mgemm<1><<<g, 512, 0, stream>>>(Ah, Al, Wf, Wraw, ldw, wstride,
                                                    bias, bstride, Cf, cstride, Ch, Cl, ldc, K, flag);
        else      k_mgemm<0><<<g, 512, 0, stream>>>(Ah, Al, Wf, Wraw, ldw, wstride,
                                                    bias, bstride, Cf, cstride, Ch, Cl, ldc, K, flag);
    };
    auto DG = [&](int relu, const float* A, int lda, const float* W, int ldw, int wcol0,
                  const float* bias, float* C, int ldc, int M, int N, int K) {
        dim3 g(N / 64, (M + 63) / 64);
        if (relu) k_dgemm<1><<<g, 256, 0, stream>>>(A, lda, W, ldw, wcol0, bias, C, ldc, M, N, K);
        else      k_dgemm<0><<<g, 256, 0, stream>>>(A, lda, W, ldw, wcol0, bias, C, ldc, M, N, K);
    };

    const int nBSD = (int)BSD;
    k_refw<<<(Sc + 255) / 256, 256, 0, stream>>>(refw);
    // layer-0: enc planes + pbuf(=enc+pos) planes, fused
    k_addf2<<<(nBSD + 255) / 256, 256, 0, stream>>>(enc, F[1], encH, encL, pbufH, pbufL, nBSD);

    // ================= encoder =================
    for (int i = 0; i < NEc; ++i) {
        MG(0, encH, encL, 2, (size_t)i * 65536, 256, F[3] + i * 256, vbuf, nullptr, nullptr,
           256, 256, 256, 1, 0, 0, 0);
        MG(0, pbufH, pbufL, 4, (size_t)i * 32768, 128, F[5] + i * 128, attnb, nullptr, nullptr,
           128, 128, 256, 1, 0, 0, 0);
        k_box_sample4<<<dim3((Sc + 3) / 4, Bc), 256, 0, stream>>>(vbuf, attnb, refw, 0,
                                                                  nullptr, tbufH, tbufL, Sc);
        MG(0, tbufH, tbufL, 6, (size_t)i * 65536, 256, F[7] + i * 256, gout, nullptr, nullptr,
           256, 256, 256, 1, 0, 0, 0);
        // LN1: y -> enc (f32) + enc planes (A of FFN1)
        k_ln<<<BSc, 256, 0, stream>>>(enc, gout, F[12] + i * 256, F[13] + i * 256,
                                      enc, encH, encL,
                                      nullptr, nullptr, nullptr, nullptr,
                                      nullptr, 0, flag);
        MG(1, encH, encL, 8, (size_t)i * 262144, 1024, F[9] + i * 1024,
           nullptr, ffnhH, ffnhL, 1024, 1024, 256, 1, 0, 0, 0);
        MG(0, ffnhH, ffnhL, 10, (size_t)i * 262144, 256, F[11] + i * 256,
           gout, nullptr, nullptr, 256, 256, 1024, 1, 0, 0, 0);
        // LN2: y -> enc + planes; pbuf planes (y+pos) for next layer
        k_ln<<<BSc, 256, 0, stream>>>(enc, gout, F[14] + i * 256, F[15] + i * 256,
                                      enc, encH, encL,
                                      (i < NEc - 1) ? F[1] : nullptr, nullptr,
                                      (i < NEc - 1) ? pbufH : nullptr,
                                      (i < NEc - 1) ? pbufL : nullptr,
                                      nullptr, 0, flag);
    }

    // ================= proposal selection =================
    k_cls<<<BSc, 256, 0, stream>>>(enc, F[36], F[37], refw, logit);
    k_topk<<<Bc, 256, 0, stream>>>(logit, idx);
    k_gather<<<dim3(NQc, Bc), 256, 0, stream>>>(enc, refw, idx, qemb, rsel);
    // batched: all 6 decoder V-projections in ONE dispatch (z = layer)
    MG(0, encH, encL, 20, 0, 256, F[21], vbuf6, nullptr, nullptr,
       256, 256, 256, NDc, 65536, 256, BSD);
    DG(0, qemb, 256, F[44], 256, 0, F[45], dt1, 256, BNQc, 256, 256);
    DG(1, qemb, 256, F[38], 256, 0, F[39], h1f, 256, BNQc, 256, 256);
    DG(1, h1f,  256, F[40], 256, 0, F[41], h2f, 256, BNQc, 256, 256);
    k_gemm4<<<(BNQc + 63) / 64, 256, 0, stream>>>(h2f, F[42], F[43], rsel, oref, BNQc, 256);
    k_qpos<<<dim3(NQc, Bc), 256, 0, stream>>>(oref, qposb);
    k_ln<<<BNQc, 256, 0, stream>>>(dt1, nullptr, F[46], F[47],
                                   xbuf, nullptr, nullptr,
                                   qposb, dqk, nullptr, nullptr,
                                   nullptr, 0, flag);   // tgt + first qk

    // ================= decoder =================
    const int nXD = BNQc * 256;
    for (int i = 0; i < NDc; ++i) {
        DG(0, dqk,  256, F[16] + (size_t)i * 196608, 768, 0,   F[17] + i * 768,       dqk512, 512, BNQc, 512, 256);
        DG(0, xbuf, 256, F[16] + (size_t)i * 196608, 768, 512, F[17] + i * 768 + 512, dv,     256, BNQc, 256, 256);
        k_mha2<<<dim3((NQc + 31) / 32, Bc, NSPL), 256, 0, stream>>>(dqk512, dv, opart, mlpart);
        k_mha_comb<<<BNQc, 256, 0, stream>>>(opart, mlpart, dt1);
        DG(0, dt1, 256, F[18] + (size_t)i * 65536, 256, 0, F[19] + i * 256, dt2, 256, BNQc, 256, 256);
        k_ln<<<BNQc, 256, 0, stream>>>(xbuf, dt2, F[30] + i * 256, F[31] + i * 256,
                                       xbuf, nullptr, nullptr,
                                       qposb, dqk, nullptr, nullptr,
                                       nullptr, 0, flag);
        DG(0, dqk, 256, F[22] + (size_t)i * 32768, 128, 0, F[23] + i * 128, datt, 128, BNQc, 128, 256);
        k_box_sample4<<<dim3((NQc + 3) / 4, Bc), 256, 0, stream>>>(vbuf6 + (size_t)i * BSD, datt,
                                                                   oref, NQc * 4,
                                                                   dt1, nullptr, nullptr, NQc);
        DG(0, dt1, 256, F[24] + (size_t)i * 65536, 256, 0, F[25] + i * 256, dt2, 256, BNQc, 256, 256);
        k_ln<<<BNQc, 256, 0, stream>>>(xbuf, dt2, F[32] + i * 256, F[33] + i * 256,
                                       xbuf, nullptr, nullptr,
                                       nullptr, nullptr, nullptr, nullptr,
                                       nullptr, 0, flag);
        DG(1, xbuf,  256,  F[26] + (size_t)i * 262144, 1024, 0, F[27] + i * 1024, dffnh, 1024, BNQc, 1024, 256);
        DG(0, dffnh, 1024, F[28] + (size_t)i * 262144, 256,  0, F[29] + i * 256,  dt2,   256,  BNQc, 256, 1024);
        k_ln<<<BNQc, 256, 0, stream>>>(xbuf, dt2, F[34] + i * 256, F[35] + i * 256,
                                       xbuf, nullptr, nullptr,
                                       (i < NDc - 1) ? qposb : nullptr,
                                       (i < NDc - 1) ? dqk : nullptr, nullptr, nullptr,
                                       d_out, (size_t)i * nXD, flag);
    }
}

// Round 14
// 2743.234 us; speedup vs baseline: 1.0673x; 1.0673x over previous
//
#include <hip/hip_runtime.h>
#include <hip/hip_bf16.h>
#include <math.h>

typedef unsigned short u16;
typedef unsigned int u32;
typedef unsigned long long u64;

#define Bc   2
#define NHc  8
#define Sc   5440
#define NQc  300
#define NEc  6
#define NDc  6
#define FFc  1024
#define BSc  (Bc*Sc)        // 10880
#define BNQc (Bc*NQc)       // 600

__device__ __forceinline__ float us2f(u16 u) {
    union { float f; unsigned v; } x; x.v = ((unsigned)u) << 16; return x.f;
}

// bf16 round-to-nearest-even (finite inputs)
__device__ __forceinline__ u16 f2bf(float f) {
    unsigned u = __float_as_uint(f);
    unsigned r = u + 0x7FFFu + ((u >> 16) & 1u);
    return (u16)(r >> 16);
}
__device__ __forceinline__ float bf2f(u16 u) { return us2f(u); }
__device__ __forceinline__ unsigned pk2(u16 a, u16 b) { return (unsigned)a | ((unsigned)b << 16); }

// k-tile-blocked plane layout: 32-k slabs, rows contiguous within a slab.
__device__ __forceinline__ size_t pidx(int row, int k) {
    return (size_t)(k >> 5) * ((size_t)BSc * 32) + ((size_t)row << 5) + (size_t)(k & 31);
}

// bijective XCD chunked swizzle (m204): contiguous ids -> same XCD's L2
__device__ __forceinline__ int xcd_swz(int orig, int nwg) {
    int xcd = orig & 7;
    int q = nwg >> 3, r = nwg & 7;
    int base = (xcd < r) ? xcd * (q + 1) : r * (q + 1) + (xcd - r) * q;
    return base + (orig >> 3);
}

using bf16x8 = __attribute__((ext_vector_type(8))) short;
using f32x4  = __attribute__((ext_vector_type(4))) float;

// ---------------- dtype detection (proven) ----------------
__global__ void k_detect(const u16* __restrict__ src, int* __restrict__ flag) {
    __shared__ int cnt;
    if (threadIdx.x == 0) cnt = 0;
    __syncthreads();
    u16 v = src[threadIdx.x];
    int e = (v >> 7) & 0xFF;
    int plaus = (e == 0) || (e >= 107 && e <= 131);
    atomicAdd(&cnt, plaus);
    __syncthreads();
    if (threadIdx.x == 0) *flag = (cnt >= 224) ? 1 : 0;
}

// ---------------- fused conversion of ALL inputs (8 elems/thread) ------------
// skip: bitmask of segments whose f32 copy is DEAD in fast(bf16) mode.
struct CvtArgs {
    const void* in[48];
    long off[48];
    int n[48];
    int cnt;
    long total;
    u64 skip;
};
__global__ void k_cvt_all8(CvtArgs args, float* __restrict__ out,
                           const int* __restrict__ flag) {
    long g = ((long)blockIdx.x * 256 + threadIdx.x) * 8;
    if (g >= args.total) return;
    int lo = 0, hi = args.cnt - 1;
    while (lo < hi) {
        int mid = (lo + hi + 1) >> 1;
        if (args.off[mid] <= g) lo = mid; else hi = mid - 1;
    }
    long local = g - args.off[lo];
    long n = (long)args.n[lo];
    float v[8];
#pragma unroll
    for (int j = 0; j < 8; ++j) v[j] = 0.f;
    if (*flag) {
        if ((args.skip >> lo) & 1) return;     // f32 copy never read in fast mode
        const u16* p = (const u16*)args.in[lo] + local;
        if (local + 8 <= n) {
            uint4 r = *(const uint4*)p;
            const u16* pu = (const u16*)&r;
#pragma unroll
            for (int j = 0; j < 8; ++j) v[j] = us2f(pu[j]);
        } else {
            for (int j = 0; j < 8; ++j)
                if (local + j < n) v[j] = us2f(p[j]);
        }
    } else {
        const float* p = (const float*)args.in[lo] + local;
        if (local + 8 <= n) {
            float4 a = ((const float4*)p)[0];
            float4 b = ((const float4*)p)[1];
            v[0] = a.x; v[1] = a.y; v[2] = a.z; v[3] = a.w;
            v[4] = b.x; v[5] = b.y; v[6] = b.z; v[7] = b.w;
        } else {
            for (int j = 0; j < 8; ++j)
                if (local + j < n) v[j] = p[j];
        }
    }
    float4 o0, o1;
    o0.x = v[0]; o0.y = v[1]; o0.z = v[2]; o0.w = v[3];
    o1.x = v[4]; o1.y = v[5]; o1.z = v[6]; o1.w = v[7];
    ((float4*)(out + g))[0] = o0;
    ((float4*)(out + g))[1] = o1;
}

// ---------------- fused prologue: enc planes + (enc+pos) planes --------------
__global__ void k_addf2(const float* __restrict__ a, const float* __restrict__ pos,
                        u16* __restrict__ ah, u16* __restrict__ al,
                        u16* __restrict__ ph, u16* __restrict__ pl, int n) {
    int i = blockIdx.x * 256 + threadIdx.x;
    if (i >= n) return;
    int row = i >> 8, k = i & 255;
    size_t px = pidx(row, k);
    float x = a[i];
    u16 h = f2bf(x);
    ah[px] = h;
    al[px] = f2bf(x - bf2f(h));
    float s = x + pos[i];
    u16 h2 = f2bf(s);
    ph[px] = h2;
    pl[px] = f2bf(s - bf2f(h2));
}

// ---------------- MFMA GEMM, blocked-plane-A, depth-1 prefetch ---------------
// C[ldc] = (Ah+Al)[BSc,K](bf16 planes, pidx layout) * W[K,N](ldw) + bias.
// M = BSc, N%128==0, K%32==0.
// blockIdx.z batches independent weight slices: W/Wraw offset z*wstride,
// C offset z*cstride (used for the 6 decoder V-projections in one dispatch).
template<int RELU>
__global__ __launch_bounds__(256) void k_mgemm(
    const u16* __restrict__ Ah, const u16* __restrict__ Al,
    const float* __restrict__ W, const u16* __restrict__ Wraw, int ldw,
    size_t wstride,
    const float* __restrict__ bias, int bstride,
    float* __restrict__ C, size_t cstride,
    u16* __restrict__ Ch, u16* __restrict__ Cl,
    int ldc, int K,
    const int* __restrict__ flag) {
    __shared__ __align__(16) u16 lsAH[4096];
    __shared__ __align__(16) u16 lsAL[4096];
    __shared__ __align__(16) u16 lsBH[4096];
    __shared__ __align__(16) u16 lsBL[4096];
    const int t = threadIdx.x;
    int lin = blockIdx.x + gridDim.x * blockIdx.y;
    lin = xcd_swz(lin, gridDim.x * gridDim.y);
    const int row0 = (lin / gridDim.x) * 128, col0 = (lin % gridDim.x) * 128;
    const int z = blockIdx.z;
    const int fast = *flag;
    const size_t PSLAB = (size_t)BSc * 32;
    W += (size_t)z * wstride;
    Wraw += (size_t)z * wstride;
    C += (size_t)z * cstride;
    bias += (size_t)z * bstride;

    // A staging: chunk c (0..511) of the contiguous 8KB slab tile.
    const int c0 = t, c1 = 256 + t;
    const size_t abase = (size_t)row0 * 32;
    const u16* a0h = Ah + abase + (size_t)c0 * 8;
    const u16* a1h = Ah + abase + (size_t)c1 * 8;
    const u16* a0l = Al + abase + (size_t)c0 * 8;
    const u16* a1l = Al + abase + (size_t)c1 * 8;
    const unsigned d0 = (((unsigned)c0 & ~3u) | (((unsigned)c0 & 3u) ^ (((unsigned)c0 >> 3) & 3u))) * 8u;
    const unsigned d1 = (((unsigned)c1 & ~3u) | (((unsigned)c1 & 3u) ^ (((unsigned)c1 >> 3) & 3u))) * 8u;

    // B staging roles: 32k x 128 cols, thread=(k-pair, col-oct)
    const int bkp = t >> 4, bno = t & 15;
    const float* bp = W + (size_t)(bkp * 2) * ldw + col0 + bno * 8;
    const u16*  brp = Wraw + (size_t)(bkp * 2) * ldw + col0 + bno * 8;

    const int lane = t & 63;
    const int w = t >> 6;
    const int wr = (w >> 1) * 64, wc = (w & 1) * 64;
    const int kg = lane >> 4, lr = lane & 15;

    unsigned iaf[4];
#pragma unroll
    for (int mi = 0; mi < 4; ++mi) {
        int arow = wr + mi * 16 + lr;
        iaf[mi] = ((unsigned)(arow << 2) + ((unsigned)kg ^ (((unsigned)arow >> 1) & 3u))) * 8u;
    }

    f32x4 acc[4][4] = {};
    uint4 aU0h, aU1h, aU0l, aU1l;
    float4 bR[4];
    uint4 bU0, bU1;
    aU0h = *(const uint4*)a0h;
    aU1h = *(const uint4*)a1h;
    aU0l = *(const uint4*)a0l;
    aU1l = *(const uint4*)a1l;
    if (fast) {
        bU0 = *(const uint4*)brp;
        bU1 = *(const uint4*)(brp + ldw);
    } else {
        const float4* q0 = (const float4*)bp;
        const float4* q1 = (const float4*)(bp + ldw);
        bR[0] = q0[0]; bR[1] = q0[1]; bR[2] = q1[0]; bR[3] = q1[1];
    }

    for (int k0 = 0; k0 < K; k0 += 32) {
        if (k0) __syncthreads();
        // ---- A: 4 vector LDS writes (contiguous per wave, conflict-free) ----
        *(uint4*)&lsAH[d0] = aU0h;
        *(uint4*)&lsAH[d1] = aU1h;
        *(uint4*)&lsAL[d0] = aU0l;
        *(uint4*)&lsAL[d1] = aU1l;
        // ---- B: transpose-stage from registers ----
        {
            unsigned bb = (unsigned)(bkp >> 2) * 1024u + (unsigned)(bkp & 3) * 2u;
            if (fast) {
                const u16* e0 = (const u16*)&bU0;
                const u16* e1 = (const u16*)&bU1;
#pragma unroll
                for (int j = 0; j < 8; ++j) {
                    int slot = bno * 8 + (j ^ (bno & 7));   // bank-spread, bijective
                    *(unsigned*)&lsBH[bb + (unsigned)slot * 8u] = pk2(e0[j], e1[j]);
                }
            } else {
                float e0f[8], e1f[8];
                *(float4*)&e0f[0] = bR[0]; *(float4*)&e0f[4] = bR[1];
                *(float4*)&e1f[0] = bR[2]; *(float4*)&e1f[4] = bR[3];
#pragma unroll
                for (int j = 0; j < 8; ++j) {
                    int slot = bno * 8 + (j ^ (bno & 7));
                    u16 h0 = f2bf(e0f[j]), h1 = f2bf(e1f[j]);
                    *(unsigned*)&lsBH[bb + (unsigned)slot * 8u] = pk2(h0, h1);
                    u16 l0 = f2bf(e0f[j] - bf2f(h0));
                    u16 l1 = f2bf(e1f[j] - bf2f(h1));
                    *(unsigned*)&lsBL[bb + (unsigned)slot * 8u] = pk2(l0, l1);
                }
            }
        }
        __syncthreads();
        // prefetch next tile into regs (overlaps fragment reads + MFMA)
        if (k0 + 32 < K) {
            size_t soff = (size_t)((k0 >> 5) + 1) * PSLAB;
            aU0h = *(const uint4*)(a0h + soff);
            aU1h = *(const uint4*)(a1h + soff);
            aU0l = *(const uint4*)(a0l + soff);
            aU1l = *(const uint4*)(a1l + soff);
            if (fast) {
                bU0 = *(const uint4*)(brp + (size_t)(k0 + 32) * ldw);
                bU1 = *(const uint4*)(brp + (size_t)(k0 + 33) * ldw);
            } else {
                const float4* q0 = (const float4*)(bp + (size_t)(k0 + 32) * ldw);
                const float4* q1 = (const float4*)(bp + (size_t)(k0 + 33) * ldw);
                bR[0] = q0[0]; bR[1] = q0[1]; bR[2] = q1[0]; bR[3] = q1[1];
            }
        }
        // ---- fragments + MFMA ----
        bf16x8 aH[4], aL[4], bH[4], bL[4];
#pragma unroll
        for (int mi = 0; mi < 4; ++mi) {
            aH[mi] = *(const bf16x8*)&lsAH[iaf[mi]];
            aL[mi] = *(const bf16x8*)&lsAL[iaf[mi]];
        }
#pragma unroll
        for (int ni = 0; ni < 4; ++ni) {
            int c = wc + ni * 16 + lr;
            int slot = (c & ~7) | ((c ^ (c >> 3)) & 7);
            unsigned ib = (unsigned)kg * 1024u + (unsigned)slot * 8u;
            bH[ni] = *(const bf16x8*)&lsBH[ib];
            if (!fast) bL[ni] = *(const bf16x8*)&lsBL[ib];
        }
#pragma unroll
        for (int mi = 0; mi < 4; ++mi)
#pragma unroll
            for (int ni = 0; ni < 4; ++ni) {
                acc[mi][ni] = __builtin_amdgcn_mfma_f32_16x16x32_bf16(aH[mi], bH[ni], acc[mi][ni], 0, 0, 0);
                acc[mi][ni] = __builtin_amdgcn_mfma_f32_16x16x32_bf16(aL[mi], bH[ni], acc[mi][ni], 0, 0, 0);
            }
        if (!fast) {
#pragma unroll
            for (int mi = 0; mi < 4; ++mi)
#pragma unroll
                for (int ni = 0; ni < 4; ++ni)
                    acc[mi][ni] = __builtin_amdgcn_mfma_f32_16x16x32_bf16(aH[mi], bL[ni], acc[mi][ni], 0, 0, 0);
        }
    }
    // ---- epilogue: C/D layout col=lane&15, row=(lane>>4)*4+reg ----
    const int rb = row0 + wr + (lane >> 4) * 4;
#pragma unroll
    for (int ni = 0; ni < 4; ++ni) {
        int cc = col0 + wc + ni * 16 + lr;
        float bv = bias[cc];
#pragma unroll
        for (int mi = 0; mi < 4; ++mi) {
#pragma unroll
            for (int r2 = 0; r2 < 4; ++r2) {
                int rr = rb + mi * 16 + r2;
                float v = acc[mi][ni][r2] + bv;
                if (RELU) v = fmaxf(v, 0.f);
                if (C) C[(size_t)rr * ldc + cc] = v;
                if (Ch) {
                    size_t px = pidx(rr, cc);
                    u16 h = f2bf(v);
                    Ch[px] = h;
                    Cl[px] = f2bf(v - bf2f(h));
                }
            }
        }
    }
}

// ---------------- double-buffered small-M GEMM: 64x64 tile, 4x4 micro --------
template<int RELU>
__global__ __launch_bounds__(256) void k_dgemm(
    const float* __restrict__ A, int lda,
    const float* __restrict__ W, int ldw, int wcol0,
    const float* __restrict__ bias,
    float* __restrict__ C, int ldc,
    int M, int N, int K) {
    __shared__ float As[2][16][68];
    __shared__ float Bs[2][16][68];
    int t = threadIdx.x;
    int row0 = blockIdx.y * 64, col0 = blockIdx.x * 64;
    int ti = t >> 4, tj = t & 15;
    int arow = t >> 2, akq = (t & 3) << 2;
    int bk = t >> 4, bn = (t & 15) << 2;
    bool aok = (row0 + arow) < M;
    const float* ap = A + (size_t)(row0 + arow) * lda + akq;
    const float* bp = W + (size_t)bk * ldw + wcol0 + col0 + bn;
    float4 aR = aok ? *(const float4*)ap : make_float4(0.f, 0.f, 0.f, 0.f);
    float4 bR = *(const float4*)bp;
    As[0][akq + 0][arow] = aR.x;
    As[0][akq + 1][arow] = aR.y;
    As[0][akq + 2][arow] = aR.z;
    As[0][akq + 3][arow] = aR.w;
    *(float4*)&Bs[0][bk][bn] = bR;
    __syncthreads();
    int cur = 0;
    float acc[4][4] = {};
    for (int k0 = 0; k0 < K; k0 += 16) {
        bool more = (k0 + 16) < K;
        if (more) {
            aR = aok ? *(const float4*)(ap + k0 + 16) : make_float4(0.f, 0.f, 0.f, 0.f);
            bR = *(const float4*)(bp + (size_t)(k0 + 16) * ldw);
        }
#pragma unroll
        for (int k = 0; k < 16; ++k) {
            float a[4], b[4];
#pragma unroll
            for (int r = 0; r < 4; ++r) a[r] = As[cur][k][ti * 4 + r];
#pragma unroll
            for (int c = 0; c < 4; ++c) b[c] = Bs[cur][k][tj * 4 + c];
#pragma unroll
            for (int r = 0; r < 4; ++r)
#pragma unroll
                for (int c = 0; c < 4; ++c) acc[r][c] += a[r] * b[c];
        }
        if (more) {
            int nxt = cur ^ 1;
            As[nxt][akq + 0][arow] = aR.x;
            As[nxt][akq + 1][arow] = aR.y;
            As[nxt][akq + 2][arow] = aR.z;
            As[nxt][akq + 3][arow] = aR.w;
            *(float4*)&Bs[nxt][bk][bn] = bR;
            __syncthreads();
            cur = nxt;
        }
    }
    for (int r = 0; r < 4; ++r) {
        int rr = row0 + ti * 4 + r;
        if (rr >= M) continue;
        for (int c = 0; c < 4; ++c) {
            int cc = col0 + tj * 4 + c;
            float v = acc[r][c] + bias[cc];
            if (RELU) v = fmaxf(v, 0.f);
            C[(size_t)rr * ldc + cc] = v;
        }
    }
}

// ---------------- bbox-head GEMM (N=4) fused with inverse_sigmoid+sigmoid ----
__global__ __launch_bounds__(256) void k_gemm4(
    const float* __restrict__ A, const float* __restrict__ W,
    const float* __restrict__ bias, const float* __restrict__ rsel,
    float* __restrict__ oref, int M, int K) {
    int row = blockIdx.x * 64 + (threadIdx.x >> 2);
    int col = threadIdx.x & 3;
    if (row >= M) return;
    float acc = 0.f;
    const float* a = A + (size_t)row * K;
    for (int k = 0; k < K; ++k) acc += a[k] * W[k * 4 + col];
    float tmp = acc + bias[col];
    float r = rsel[(size_t)row * 4 + col];
    r = fminf(fmaxf(r, 1e-5f), 1.f - 1e-5f);
    float v = tmp + logf(r / (1.f - r));
    oref[(size_t)row * 4 + col] = 1.f / (1.f + __expf(-v));
}

// ---------------- LayerNorm (residual; optional plane outs; optional store) --
__global__ void k_ln(const float* __restrict__ a, const float* __restrict__ b,
                     const float* __restrict__ g, const float* __restrict__ be,
                     float* __restrict__ o,
                     u16* __restrict__ oh, u16* __restrict__ ol,
                     const float* __restrict__ padd, float* __restrict__ opadd,
                     u16* __restrict__ oph, u16* __restrict__ opl,
                     void* __restrict__ sdst, size_t soff,
                     const int* __restrict__ flag) {
    int row = blockIdx.x;
    int t = threadIdx.x;
    __shared__ float red[256];
    size_t ix = (size_t)row * 256 + t;
    float x = a[ix];
    if (b) x += b[ix];
    red[t] = x;
    __syncthreads();
    for (int s = 128; s > 0; s >>= 1) { if (t < s) red[t] += red[t + s]; __syncthreads(); }
    float mean = red[0] / 256.f;
    __syncthreads();
    float d = x - mean;
    red[t] = d * d;
    __syncthreads();
    for (int s = 128; s > 0; s >>= 1) { if (t < s) red[t] += red[t + s]; __syncthreads(); }
    float var = red[0] / 256.f;
    float y = d * rsqrtf(var + 1e-5f) * g[t] + be[t];
    o[ix] = y;
    if (oh) {
        size_t px = pidx(row, t);
        u16 h = f2bf(y);
        oh[px] = h;
        ol[px] = f2bf(y - bf2f(h));
    }
    if (padd) {
        float z = y + padd[ix];
        if (opadd) opadd[ix] = z;
        if (oph) {
            size_t px = pidx(row, t);
            u16 h = f2bf(z);
            oph[px] = h;
            opl[px] = f2bf(z - bf2f(h));
        }
    }
    if (sdst) {
        if (*flag) ((__hip_bfloat16*)sdst)[soff + ix] = __float2bfloat16(y);
        else       ((float*)sdst)[soff + ix] = y;
    }
}

// ---------------- ref windows ----------------
__global__ void k_refw(float* __restrict__ rw) {
    int s = blockIdx.x * 256 + threadIdx.x;
    if (s >= Sc) return;
    int start, HW;
    if (s < 4096)      { start = 0;    HW = 64; }
    else if (s < 5120) { start = 4096; HW = 32; }
    else if (s < 5376) { start = 5120; HW = 16; }
    else               { start = 5376; HW = 8;  }
    int loc = s - start;
    int i = loc / HW, j = loc % HW;
    rw[s * 4 + 0] = (j + 0.5f) / ((float)HW + 1e-6f);
    rw[s * 4 + 1] = (i + 0.5f) / ((float)HW + 1e-6f);
    rw[s * 4 + 2] = 4.0f / (float)HW;
    rw[s * 4 + 3] = 4.0f / (float)HW;
}

// ---------------- box attention sampling v4: wave/query, float4 channels ------
__global__ __launch_bounds__(256) void k_box_sample4(
    const float* __restrict__ v, const float* __restrict__ attn,
    const float* __restrict__ refw, int ref_bs,
    float* __restrict__ out, u16* __restrict__ outh, u16* __restrict__ outl,
    int N) {
    const int t = threadIdx.x;
    const int qi = t >> 6, lane = t & 63;
    const int blk = xcd_swz(blockIdx.x, gridDim.x);
    const int n = blk * 4 + qi;
    const int b = blockIdx.y;
    if (n >= N) return;                       // wave-uniform
    const float* arow = attn + ((size_t)b * N + n) * 128;
    float2 wl = *(const float2*)(arow + lane * 2);
    float m = fmaxf(wl.x, wl.y);
#pragma unroll
    for (int d2 = 1; d2 < 8; d2 <<= 1) m = fmaxf(m, __shfl_xor(m, d2, 8));
    float e0 = __expf(wl.x - m), e1 = __expf(wl.y - m);
    float s = e0 + e1;
#pragma unroll
    for (int d2 = 1; d2 < 8; d2 <<= 1) s += __shfl_xor(s, d2, 8);
    float inv = 1.f / s;
    e0 *= inv; e1 *= inv;

    const float* rw = refw + (size_t)ref_bs * b + (size_t)n * 4;
    float cx = rw[0], cy = rw[1], bw = rw[2], bh = rw[3];
    const float* vb = v + (size_t)b * Sc * 256 + lane * 4;
    float4 acc = make_float4(0.f, 0.f, 0.f, 0.f);
    int start = 0;
    const int HWs[4] = {64, 32, 16, 8};
#pragma unroll
    for (int l = 0; l < 4; ++l) {
        int HW = HWs[l];
#pragma unroll
        for (int p = 0; p < 4; ++p) {
            float gx = (p & 1) ? 0.25f : -0.25f;
            float gy = (p >> 1) ? 0.25f : -0.25f;
            float x = (cx + gx * bw) * (float)HW - 0.5f;
            float y = (cy + gy * bh) * (float)HW - 0.5f;
            float x0f = floorf(x), y0f = floorf(y);
            float wx = x - x0f, wy = y - y0f;
            int x0 = (int)x0f, y0 = (int)y0f;
            float4 smp = make_float4(0.f, 0.f, 0.f, 0.f);
            if (x0 >= 0 && x0 < HW && y0 >= 0 && y0 < HW) {
                float4 g4 = *(const float4*)(vb + (size_t)(start + y0 * HW + x0) * 256);
                float wgt = (1.f - wx) * (1.f - wy);
                smp.x += wgt * g4.x; smp.y += wgt * g4.y; smp.z += wgt * g4.z; smp.w += wgt * g4.w;
            }
            if (x0 + 1 >= 0 && x0 + 1 < HW && y0 >= 0 && y0 < HW) {
                float4 g4 = *(const float4*)(vb + (size_t)(start + y0 * HW + x0 + 1) * 256);
                float wgt = wx * (1.f - wy);
                smp.x += wgt * g4.x; smp.y += wgt * g4.y; smp.z += wgt * g4.z; smp.w += wgt * g4.w;
            }
            if (x0 >= 0 && x0 < HW && y0 + 1 >= 0 && y0 + 1 < HW) {
                float4 g4 = *(const float4*)(vb + (size_t)(start + (y0 + 1) * HW + x0) * 256);
                float wgt = (1.f - wx) * wy;
                smp.x += wgt * g4.x; smp.y += wgt * g4.y; smp.z += wgt * g4.z; smp.w += wgt * g4.w;
            }
            if (x0 + 1 >= 0 && x0 + 1 < HW && y0 + 1 >= 0 && y0 + 1 < HW) {
                float4 g4 = *(const float4*)(vb + (size_t)(start + (y0 + 1) * HW + x0 + 1) * 256);
                float wgt = wx * wy;
                smp.x += wgt * g4.x; smp.y += wgt * g4.y; smp.z += wgt * g4.z; smp.w += wgt * g4.w;
            }
            const int idx = l * 4 + p;
            float wsel = (idx & 1) ? e1 : e0;
            float wv = __shfl(wsel, (lane & ~7) | (idx >> 1), 64);
            acc.x += wv * smp.x; acc.y += wv * smp.y;
            acc.z += wv * smp.z; acc.w += wv * smp.w;
        }
        start += HW * HW;
    }
    if (out) {
        size_t obase = ((size_t)b * N + n) * 256 + lane * 4;
        *(float4*)(out + obase) = acc;
    }
    if (outh) {
        size_t px = pidx(b * N + n, lane * 4);
        ushort4 h, lo;
        h.x = f2bf(acc.x); h.y = f2bf(acc.y); h.z = f2bf(acc.z); h.w = f2bf(acc.w);
        lo.x = f2bf(acc.x - bf2f(h.x)); lo.y = f2bf(acc.y - bf2f(h.y));
        lo.z = f2bf(acc.z - bf2f(h.z)); lo.w = f2bf(acc.w - bf2f(h.w));
        *(ushort4*)(outh + px) = h;
        *(ushort4*)(outl + px) = lo;
    }
}

// ---------------- cls logits + valid mask ----------------
__global__ void k_cls(const float* __restrict__ x, const float* __restrict__ w,
                      const float* __restrict__ cb, const float* __restrict__ rw,
                      float* __restrict__ logits) {
    int row = blockIdx.x;
    int t = threadIdx.x;
    __shared__ float red[256];
    red[t] = x[(size_t)row * 256 + t] * w[t];
    __syncthreads();
    for (int s = 128; s > 0; s >>= 1) { if (t < s) red[t] += red[t + s]; __syncthreads(); }
    if (t == 0) {
        int s = row % Sc;
        float cx = rw[s * 4], cy = rw[s * 4 + 1];
        bool valid = (cx > 0.01f) && (cx < 0.99f) && (cy > 0.01f) && (cy < 0.99f);
        logits[row] = valid ? (red[0] + cb[0]) : -65504.0f;
    }
}

// ---------------- exact top-k: radix select (parallel suffix scan) + rank emit
__global__ void k_topk(const float* __restrict__ logits, int* __restrict__ idxout) {
    int b = blockIdx.x;
    int t = threadIdx.x;
    __shared__ unsigned keys[Sc];
    __shared__ int hist[256];
    __shared__ int suf[257];
    __shared__ unsigned sprefix;
    __shared__ int sR;
    __shared__ int cnt;
    __shared__ u64 cand[512];
    for (int i = t; i < Sc; i += 256) {
        union { float f; unsigned u; } x;
        x.f = logits[(size_t)b * Sc + i];
        unsigned u = x.u;
        keys[i] = (u & 0x80000000u) ? ~u : (u | 0x80000000u);
    }
    if (t == 0) { sprefix = 0; sR = NQc; suf[256] = 0; }
    __syncthreads();
    for (int shift = 24; shift >= 0; shift -= 8) {
        hist[t] = 0;
        __syncthreads();
        unsigned pref = sprefix;
        int R = sR;
        unsigned pmask = (shift == 24) ? 0u : (0xFFFFFFFFu << (shift + 8));
        for (int i = t; i < Sc; i += 256) {
            unsigned kk = keys[i];
            if ((kk & pmask) == (pref & pmask))
                atomicAdd(&hist[(kk >> shift) & 255], 1);
        }
        __syncthreads();
        suf[t] = hist[t];
        __syncthreads();
        for (int s2 = 1; s2 < 256; s2 <<= 1) {
            int vv = suf[t] + ((t + s2 < 256) ? suf[t + s2] : 0);
            __syncthreads();
            suf[t] = vv;
            __syncthreads();
        }
        if (suf[t] >= R && suf[t + 1] < R) {
            sR = R - suf[t + 1];
            sprefix = pref | ((unsigned)t << shift);
        }
        __syncthreads();
    }
    unsigned T = sprefix;
    if (t == 0) cnt = 0;
    __syncthreads();
    for (int i = t; i < Sc; i += 256) {
        unsigned kk = keys[i];
        if (kk >= T) {
            int slot = atomicAdd(&cnt, 1);
            if (slot < 512)
                cand[slot] = ~((((u64)kk) << 32) | (u64)(0xFFFFFFFFu - (unsigned)i));
        }
    }
    __syncthreads();
    int total = cnt < 512 ? cnt : 512;
    for (int i = t; i < 512; i += 256)
        if (i >= total) cand[i] = 0xFFFFFFFFFFFFFFFFull;
    __syncthreads();
    for (int i = t; i < 512; i += 256) {
        if (i >= total) continue;
        u64 mine = cand[i];
        int rank = 0;
        for (int j = 0; j < 512; ++j) rank += (cand[j] < mine) ? 1 : 0;
        if (rank < NQc) {
            u64 c = ~mine;
            idxout[b * NQc + rank] = (int)(0xFFFFFFFFu - (unsigned)(c & 0xFFFFFFFFull));
        }
    }
}

// ---------------- gather selected rows + ref windows ----------------
__global__ void k_gather(const float* __restrict__ x, const float* __restrict__ rw,
                         const int* __restrict__ idx, float* __restrict__ qemb,
                         float* __restrict__ refsel) {
    int q = blockIdx.x, b = blockIdx.y;
    int t = threadIdx.x;
    int id = idx[b * NQc + q];
    qemb[((size_t)b * NQc + q) * 256 + t] = x[((size_t)b * Sc + id) * 256 + t];
    if (t < 4) refsel[((size_t)b * NQc + q) * 4 + t] = rw[id * 4 + t];
}

// ---------------- sine positional embedding of boxes ----------------
__global__ void k_qpos(const float* __restrict__ outref, float* __restrict__ qpos) {
    int n = blockIdx.x, b = blockIdx.y;
    int t = threadIdx.x;
    const float* orf = outref + ((size_t)b * NQc + n) * 4;
    int c = t >> 7;
    int j = (t & 127) >> 1;
    int si = t & 1;
    float tj = powf(10000.f, (float)j / 64.f);
    float sc = 6.283185307179586f / tj;
    float v1 = orf[c] * sc;
    float v2 = orf[2 + c] * sc;
    float r = si ? (cosf(v1) + cosf(v2)) : (sinf(v1) + sinf(v2));
    qpos[((size_t)b * NQc + n) * 256 + t] = r;
}

// ---------------- MHA v3: thread=(query,head), 10-way key split (300=10x30) --
#define NSPL 10
#define SPLW 30
__global__ __launch_bounds__(256) void k_mha2(
    const float* __restrict__ qk, const float* __restrict__ v,
    float* __restrict__ opart, float* __restrict__ mlpart) {
    __shared__ float lsK[SPLW][256];
    __shared__ float lsV[SPLW][256];
    const int t = threadIdx.x;
    const int h = t >> 5, ql = t & 31;
    const int b = blockIdx.y, z = blockIdx.z;
    const int n = blockIdx.x * 32 + ql;
    const bool qok = n < NQc;
    const int kstart = z * SPLW;
    for (int f = t; f < SPLW * 64; f += 256) {
        int r = f >> 6, c4 = f & 63;
        int krow = kstart + r;
        float4 kv = *(const float4*)(qk + (size_t)(b * NQc + krow) * 512 + 256 + c4 * 4);
        float4 vv = *(const float4*)(v + (size_t)(b * NQc + krow) * 256 + c4 * 4);
        *(float4*)&lsK[r][c4 * 4] = kv;
        *(float4*)&lsV[r][c4 * 4] = vv;
    }
    __syncthreads();
    float q[32];
    {
        const float* qp = qk + (size_t)(b * NQc + (qok ? n : 0)) * 512 + h * 32;
#pragma unroll
        for (int j4 = 0; j4 < 8; ++j4) {
            float4 f = ((const float4*)qp)[j4];
            q[j4 * 4 + 0] = f.x; q[j4 * 4 + 1] = f.y;
            q[j4 * 4 + 2] = f.z; q[j4 * 4 + 3] = f.w;
        }
    }
    const float scale = 0.17677669529663688f;
    float s[SPLW];
#pragma unroll
    for (int kk = 0; kk < SPLW; ++kk) {
        float acc = 0.f;
        const float* kr = &lsK[kk][h * 32];
#pragma unroll
        for (int j4 = 0; j4 < 8; ++j4) {
            float4 kf = ((const float4*)kr)[j4];
            acc += q[j4*4+0]*kf.x + q[j4*4+1]*kf.y + q[j4*4+2]*kf.z + q[j4*4+3]*kf.w;
        }
        s[kk] = acc * scale;
    }
    float m = s[0];
#pragma unroll
    for (int kk = 1; kk < SPLW; ++kk) m = fmaxf(m, s[kk]);
    float o[32];
#pragma unroll
    for (int j = 0; j < 32; ++j) o[j] = 0.f;
    float l = 0.f;
#pragma unroll
    for (int kk = 0; kk < SPLW; ++kk) {
        float e = __expf(s[kk] - m);
        l += e;
        const float* vr = &lsV[kk][h * 32];
#pragma unroll
        for (int j4 = 0; j4 < 8; ++j4) {
            float4 vf = ((const float4*)vr)[j4];
            o[j4*4+0] += e * vf.x; o[j4*4+1] += e * vf.y;
            o[j4*4+2] += e * vf.z; o[j4*4+3] += e * vf.w;
        }
    }
    if (qok) {
        float* op = opart + ((size_t)z * BNQc + (size_t)b * NQc + n) * 256 + h * 32;
#pragma unroll
        for (int j4 = 0; j4 < 8; ++j4) {
            float4 f;
            f.x = o[j4*4+0]; f.y = o[j4*4+1]; f.z = o[j4*4+2]; f.w = o[j4*4+3];
            ((float4*)op)[j4] = f;
        }
        float* mlp = mlpart + ((size_t)z * BNQc + (size_t)b * NQc + n) * 16 + h * 2;
        mlp[0] = m; mlp[1] = l;
    }
}

__global__ void k_mha_comb(const float* __restrict__ opart, const float* __restrict__ mlpart,
                           float* __restrict__ out) {
    int row = blockIdx.x;           // b*NQc + n over BNQc
    int t = threadIdx.x;
    int h = t >> 5;
    float mm[NSPL], ll[NSPL];
    float M = -3.0e38f;
#pragma unroll
    for (int z = 0; z < NSPL; ++z) {
        mm[z] = mlpart[((size_t)z * BNQc + row) * 16 + h * 2];
        ll[z] = mlpart[((size_t)z * BNQc + row) * 16 + h * 2 + 1];
        M = fmaxf(M, mm[z]);
    }
    float denom = 0.f, osum = 0.f;
#pragma unroll
    for (int z = 0; z < NSPL; ++z) {
        float a = __expf(mm[z] - M);
        denom += ll[z] * a;
        osum += opart[((size_t)z * BNQc + row) * 256 + t] * a;
    }
    out[(size_t)row * 256 + t] = osum / denom;
}

// =====================================================================
extern "C" void kernel_launch(void* const* d_in, const int* in_sizes, int n_in,
                              void* d_out, int out_size, void* d_ws, size_t ws_size,
                              hipStream_t stream) {
    char* base = (char*)d_ws;
    size_t off = 0;
    auto allocB = [&](size_t bytes) {
        char* p = base + off;
        off = (off + bytes + 255) & ~(size_t)255;
        return p;
    };
    int* flag = (int*)allocB(16);
    auto allocF = [&](size_t n) { return (float*)allocB(n * 4); };
    auto allocH = [&](size_t n) { return (u16*)allocB(n * 2); };

    k_detect<<<1, 256, 0, stream>>>((const u16*)d_in[0], flag);

    // ---- one fused conversion of all 48 inputs ----
    CvtArgs ca;
    long acc = 0;
    int ninp = n_in < 48 ? n_in : 48;
    for (int i = 0; i < 48; ++i) {
        int idx2 = i < ninp ? i : ninp - 1;
        ca.in[i] = d_in[idx2];
        ca.n[i] = (i < ninp) ? in_sizes[i] : 0;
        ca.off[i] = acc;
        acc += ((long)ca.n[i] + 63) & ~63L;
    }
    ca.cnt = 48;
    ca.total = acc;
    // f32 copies of these segments are dead when inputs are bf16 (mgemm Wraw path)
    ca.skip = (1ull << 2) | (1ull << 4) | (1ull << 6) | (1ull << 8) |
              (1ull << 10) | (1ull << 20);
    float* cvtbase = allocF((size_t)acc);
    k_cvt_all8<<<(int)((acc / 8 + 255) / 256), 256, 0, stream>>>(ca, cvtbase, flag);
    float* F[48];
    for (int i = 0; i < 48; ++i) F[i] = cvtbase + ca.off[i];

    // ---- activation buffers ----
    const size_t BSD = (size_t)BSc * 256;
    float* enc    = F[0];                 // f32 activation (in-place)
    u16* encH  = allocH(BSD);  u16* encL  = allocH(BSD);
    u16* pbufH = allocH(BSD);  u16* pbufL = allocH(BSD);
    u16* tbufH = allocH(BSD);  u16* tbufL = allocH(BSD);
    u16* ffnhH = allocH((size_t)BSc * FFc);
    u16* ffnhL = allocH((size_t)BSc * FFc);
    float* vbuf   = allocF(BSD);               // encoder value buffer
    float* vbuf6  = allocF((size_t)NDc * BSD); // 6 decoder value buffers
    float* gout   = allocF(BSD);
    float* attnb  = allocF((size_t)BSc * 128);
    float* refw   = allocF(Sc * 4);
    float* logit  = allocF(BSc);
    int*   idx    = (int*)allocB(BNQc * 4);
    float* qemb   = allocF((size_t)BNQc * 256);
    float* rsel   = allocF(BNQc * 4);
    float* xbuf   = allocF((size_t)BNQc * 256);
    float* qposb  = allocF((size_t)BNQc * 256);
    float* dqk    = allocF((size_t)BNQc * 256);
    float* dqk512 = allocF((size_t)BNQc * 512);
    float* dv     = allocF((size_t)BNQc * 256);
    float* dt1    = allocF((size_t)BNQc * 256);
    float* dt2    = allocF((size_t)BNQc * 256);
    float* datt   = allocF((size_t)BNQc * 128);
    float* dffnh  = allocF((size_t)BNQc * FFc);
    float* h1f    = allocF((size_t)BNQc * 256);
    float* h2f    = allocF((size_t)BNQc * 256);
    float* oref   = allocF(BNQc * 4);
    float* opart  = allocF((size_t)NSPL * BNQc * 256);
    float* mlpart = allocF((size_t)NSPL * BNQc * 16);
    (void)ws_size; (void)out_size;

    auto MG = [&](int relu, const u16* Ah, const u16* Al, int widx, size_t woff, int ldw,
                  const float* bias, float* Cf, u16* Ch, u16* Cl, int ldc, int N, int K,
                  int nz, size_t wstride, int bstride, size_t cstride) {
        const float* Wf = F[widx] + woff;
        const u16* Wraw = (const u16*)d_in[widx] + woff;
        dim3 g(N / 128, BSc / 128, nz);
        if (relu) k_mgemm<1><<<g, 256, 0, stream>>>(Ah, Al, Wf, Wraw, ldw, wstride,
                                                    bias, bstride, Cf, cstride, Ch, Cl, ldc, K, flag);
        else      k_mgemm<0><<<g, 256, 0, stream>>>(Ah, Al, Wf, Wraw, ldw, wstride,
                                                    bias, bstride, Cf, cstride, Ch, Cl, ldc, K, flag);
    };
    auto DG = [&](int relu, const float* A, int lda, const float* W, int ldw, int wcol0,
                  const float* bias, float* C, int ldc, int M, int N, int K) {
        dim3 g(N / 64, (M + 63) / 64);
        if (relu) k_dgemm<1><<<g, 256, 0, stream>>>(A, lda, W, ldw, wcol0, bias, C, ldc, M, N, K);
        else      k_dgemm<0><<<g, 256, 0, stream>>>(A, lda, W, ldw, wcol0, bias, C, ldc, M, N, K);
    };

    const int nBSD = (int)BSD;
    k_refw<<<(Sc + 255) / 256, 256, 0, stream>>>(refw);
    // layer-0: enc planes + pbuf(=enc+pos) planes, fused
    k_addf2<<<(nBSD + 255) / 256, 256, 0, stream>>>(enc, F[1], encH, encL, pbufH, pbufL, nBSD);

    // ================= encoder =================
    for (int i = 0; i < NEc; ++i) {
        MG(0, encH, encL, 2, (size_t)i * 65536, 256, F[3] + i * 256, vbuf, nullptr, nullptr,
           256, 256, 256, 1, 0, 0, 0);
        MG(0, pbufH, pbufL, 4, (size_t)i * 32768, 128, F[5] + i * 128, attnb, nullptr, nullptr,
           128, 128, 256, 1, 0, 0, 0);
        k_box_sample4<<<dim3((Sc + 3) / 4, Bc), 256, 0, stream>>>(vbuf, attnb, refw, 0,
                                                                  nullptr, tbufH, tbufL, Sc);
        MG(0, tbufH, tbufL, 6, (size_t)i * 65536, 256, F[7] + i * 256, gout, nullptr, nullptr,
           256, 256, 256, 1, 0, 0, 0);
        // LN1: y -> enc (f32) + enc planes (A of FFN1)
        k_ln<<<BSc, 256, 0, stream>>>(enc, gout, F[12] + i * 256, F[13] + i * 256,
                                      enc, encH, encL,
                                      nullptr, nullptr, nullptr, nullptr,
                                      nullptr, 0, flag);
        MG(1, encH, encL, 8, (size_t)i * 262144, 1024, F[9] + i * 1024,
           nullptr, ffnhH, ffnhL, 1024, 1024, 256, 1, 0, 0, 0);
        MG(0, ffnhH, ffnhL, 10, (size_t)i * 262144, 256, F[11] + i * 256,
           gout, nullptr, nullptr, 256, 256, 1024, 1, 0, 0, 0);
        // LN2: y -> enc + planes; pbuf planes (y+pos) for next layer
        k_ln<<<BSc, 256, 0, stream>>>(enc, gout, F[14] + i * 256, F[15] + i * 256,
                                      enc, encH, encL,
                                      (i < NEc - 1) ? F[1] : nullptr, nullptr,
                                      (i < NEc - 1) ? pbufH : nullptr,
                                      (i < NEc - 1) ? pbufL : nullptr,
                                      nullptr, 0, flag);
    }

    // ================= proposal selection =================
    k_cls<<<BSc, 256, 0, stream>>>(enc, F[36], F[37], refw, logit);
    k_topk<<<Bc, 256, 0, stream>>>(logit, idx);
    k_gather<<<dim3(NQc, Bc), 256, 0, stream>>>(enc, refw, idx, qemb, rsel);
    // batched: all 6 decoder V-projections in ONE dispatch (z = layer)
    MG(0, encH, encL, 20, 0, 256, F[21], vbuf6, nullptr, nullptr,
       256, 256, 256, NDc, 65536, 256, BSD);
    DG(0, qemb, 256, F[44], 256, 0, F[45], dt1, 256, BNQc, 256, 256);
    DG(1, qemb, 256, F[38], 256, 0, F[39], h1f, 256, BNQc, 256, 256);
    DG(1, h1f,  256, F[40], 256, 0, F[41], h2f, 256, BNQc, 256, 256);
    k_gemm4<<<(BNQc + 63) / 64, 256, 0, stream>>>(h2f, F[42], F[43], rsel, oref, BNQc, 256);
    k_qpos<<<dim3(NQc, Bc), 256, 0, stream>>>(oref, qposb);
    k_ln<<<BNQc, 256, 0, stream>>>(dt1, nullptr, F[46], F[47],
                                   xbuf, nullptr, nullptr,
                                   qposb, dqk, nullptr, nullptr,
                                   nullptr, 0, flag);   // tgt + first qk

    // ================= decoder =================
    const int nXD = BNQc * 256;
    for (int i = 0; i < NDc; ++i) {
        DG(0, dqk,  256, F[16] + (size_t)i * 196608, 768, 0,   F[17] + i * 768,       dqk512, 512, BNQc, 512, 256);
        DG(0, xbuf, 256, F[16] + (size_t)i * 196608, 768, 512, F[17] + i * 768 + 512, dv,     256, BNQc, 256, 256);
        k_mha2<<<dim3((NQc + 31) / 32, Bc, NSPL), 256, 0, stream>>>(dqk512, dv, opart, mlpart);
        k_mha_comb<<<BNQc, 256, 0, stream>>>(opart, mlpart, dt1);
        DG(0, dt1, 256, F[18] + (size_t)i * 65536, 256, 0, F[19] + i * 256, dt2, 256, BNQc, 256, 256);
        k_ln<<<BNQc, 256, 0, stream>>>(xbuf, dt2, F[30] + i * 256, F[31] + i * 256,
                                       xbuf, nullptr, nullptr,
                                       qposb, dqk, nullptr, nullptr,
                                       nullptr, 0, flag);
        DG(0, dqk, 256, F[22] + (size_t)i * 32768, 128, 0, F[23] + i * 128, datt, 128, BNQc, 128, 256);
        k_box_sample4<<<dim3((NQc + 3) / 4, Bc), 256, 0, stream>>>(vbuf6 + (size_t)i * BSD, datt,
                                                                   oref, NQc * 4,
                                                                   dt1, nullptr, nullptr, NQc);
        DG(0, dt1, 256, F[24] + (size_t)i * 65536, 256, 0, F[25] + i * 256, dt2, 256, BNQc, 256, 256);
        k_ln<<<BNQc, 256, 0, stream>>>(xbuf, dt2, F[32] + i * 256, F[33] + i * 256,
                                       xbuf, nullptr, nullptr,
                                       nullptr, nullptr, nullptr, nullptr,
                                       nullptr, 0, flag);
        DG(1, xbuf,  256,  F[26] + (size_t)i * 262144, 1024, 0, F[27] + i * 1024, dffnh, 1024, BNQc, 1024, 256);
        DG(0, dffnh, 1024, F[28] + (size_t)i * 262144, 256,  0, F[29] + i * 256,  dt2,   256,  BNQc, 256, 1024);
        k_ln<<<BNQc, 256, 0, stream>>>(xbuf, dt2, F[34] + i * 256, F[35] + i * 256,
                                       xbuf, nullptr, nullptr,
                                       (i < NDc - 1) ? qposb : nullptr,
                                       (i < NDc - 1) ? dqk : nullptr, nullptr, nullptr,
                                       d_out, (size_t)i * nXD, flag);
    }
}

// Round 15
// 2651.703 us; speedup vs baseline: 1.1041x; 1.0345x over previous
//
#include <hip/hip_runtime.h>
#include <hip/hip_bf16.h>
#include <math.h>

typedef unsigned short u16;
typedef unsigned int u32;
typedef unsigned long long u64;

#define Bc   2
#define NHc  8
#define Sc   5440
#define NQc  300
#define NEc  6
#define NDc  6
#define FFc  1024
#define BSc  (Bc*Sc)        // 10880
#define BNQc (Bc*NQc)       // 600

__device__ __forceinline__ float us2f(u16 u) {
    union { float f; unsigned v; } x; x.v = ((unsigned)u) << 16; return x.f;
}

// bf16 round-to-nearest-even (finite inputs)
__device__ __forceinline__ u16 f2bf(float f) {
    unsigned u = __float_as_uint(f);
    unsigned r = u + 0x7FFFu + ((u >> 16) & 1u);
    return (u16)(r >> 16);
}
__device__ __forceinline__ float bf2f(u16 u) { return us2f(u); }
__device__ __forceinline__ unsigned pk2(u16 a, u16 b) { return (unsigned)a | ((unsigned)b << 16); }

// k-tile-blocked plane layout: 32-k slabs, rows contiguous within a slab.
__device__ __forceinline__ size_t pidx(int row, int k) {
    return (size_t)(k >> 5) * ((size_t)BSc * 32) + ((size_t)row << 5) + (size_t)(k & 31);
}

// bijective XCD chunked swizzle (m204): contiguous ids -> same XCD's L2
__device__ __forceinline__ int xcd_swz(int orig, int nwg) {
    int xcd = orig & 7;
    int q = nwg >> 3, r = nwg & 7;
    int base = (xcd < r) ? xcd * (q + 1) : r * (q + 1) + (xcd - r) * q;
    return base + (orig >> 3);
}

using bf16x8 = __attribute__((ext_vector_type(8))) short;
using f32x4  = __attribute__((ext_vector_type(4))) float;

// ---------------- dtype detection (proven) ----------------
__global__ void k_detect(const u16* __restrict__ src, int* __restrict__ flag) {
    __shared__ int cnt;
    if (threadIdx.x == 0) cnt = 0;
    __syncthreads();
    u16 v = src[threadIdx.x];
    int e = (v >> 7) & 0xFF;
    int plaus = (e == 0) || (e >= 107 && e <= 131);
    atomicAdd(&cnt, plaus);
    __syncthreads();
    if (threadIdx.x == 0) *flag = (cnt >= 224) ? 1 : 0;
}

// ---------------- fused conversion of ALL inputs (8 elems/thread) ------------
// skip: bitmask of segments whose f32 copy is DEAD in fast(bf16) mode.
struct CvtArgs {
    const void* in[48];
    long off[48];
    int n[48];
    int cnt;
    long total;
    u64 skip;
};
__global__ void k_cvt_all8(CvtArgs args, float* __restrict__ out,
                           const int* __restrict__ flag) {
    long g = ((long)blockIdx.x * 256 + threadIdx.x) * 8;
    if (g >= args.total) return;
    int lo = 0, hi = args.cnt - 1;
    while (lo < hi) {
        int mid = (lo + hi + 1) >> 1;
        if (args.off[mid] <= g) lo = mid; else hi = mid - 1;
    }
    long local = g - args.off[lo];
    long n = (long)args.n[lo];
    float v[8];
#pragma unroll
    for (int j = 0; j < 8; ++j) v[j] = 0.f;
    if (*flag) {
        if ((args.skip >> lo) & 1) return;     // f32 copy never read in fast mode
        const u16* p = (const u16*)args.in[lo] + local;
        if (local + 8 <= n) {
            uint4 r = *(const uint4*)p;
            const u16* pu = (const u16*)&r;
#pragma unroll
            for (int j = 0; j < 8; ++j) v[j] = us2f(pu[j]);
        } else {
            for (int j = 0; j < 8; ++j)
                if (local + j < n) v[j] = us2f(p[j]);
        }
    } else {
        const float* p = (const float*)args.in[lo] + local;
        if (local + 8 <= n) {
            float4 a = ((const float4*)p)[0];
            float4 b = ((const float4*)p)[1];
            v[0] = a.x; v[1] = a.y; v[2] = a.z; v[3] = a.w;
            v[4] = b.x; v[5] = b.y; v[6] = b.z; v[7] = b.w;
        } else {
            for (int j = 0; j < 8; ++j)
                if (local + j < n) v[j] = p[j];
        }
    }
    float4 o0, o1;
    o0.x = v[0]; o0.y = v[1]; o0.z = v[2]; o0.w = v[3];
    o1.x = v[4]; o1.y = v[5]; o1.z = v[6]; o1.w = v[7];
    ((float4*)(out + g))[0] = o0;
    ((float4*)(out + g))[1] = o1;
}

// ---------------- fused prologue: enc planes + (enc+pos) planes --------------
__global__ void k_addf2(const float* __restrict__ a, const float* __restrict__ pos,
                        u16* __restrict__ ah, u16* __restrict__ al,
                        u16* __restrict__ ph, u16* __restrict__ pl, int n) {
    int i = blockIdx.x * 256 + threadIdx.x;
    if (i >= n) return;
    int row = i >> 8, k = i & 255;
    size_t px = pidx(row, k);
    float x = a[i];
    u16 h = f2bf(x);
    ah[px] = h;
    al[px] = f2bf(x - bf2f(h));
    float s = x + pos[i];
    u16 h2 = f2bf(s);
    ph[px] = h2;
    pl[px] = f2bf(s - bf2f(h2));
}

// ---------------- MFMA GEMM, blocked-plane-A, depth-1 prefetch ---------------
// C[ldc] = (Ah+Al)[BSc,K](bf16 planes, pidx layout) * W[K,N](ldw) + bias.
// M = BSc, N%128==0, K%32==0.
// blockIdx.z batching, two modes:
//   Ah2==null: z selects weight slice (W/Wraw += z*wstride, C += z*cstride).
//   Ah2!=null: z==1 runs a SECOND independent GEMM (Ah2*W2->C2, 128 cols:
//              only col-block 0 is valid; others exit). Used to co-schedule
//              the encoder's value- and attention-projections in one dispatch.
template<int RELU>
__global__ __launch_bounds__(256) void k_mgemm(
    const u16* __restrict__ Ah, const u16* __restrict__ Al,
    const float* __restrict__ W, const u16* __restrict__ Wraw, int ldw,
    size_t wstride,
    const float* __restrict__ bias, int bstride,
    float* __restrict__ C, size_t cstride,
    u16* __restrict__ Ch, u16* __restrict__ Cl,
    int ldc, int K,
    const int* __restrict__ flag,
    const u16* __restrict__ Ah2, const u16* __restrict__ Al2,
    const float* __restrict__ W2, const u16* __restrict__ W2raw, int ldw2,
    const float* __restrict__ bias2, float* __restrict__ C2, int ldc2) {
    __shared__ __align__(16) u16 lsAH[4096];
    __shared__ __align__(16) u16 lsAL[4096];
    __shared__ __align__(16) u16 lsBH[4096];
    __shared__ __align__(16) u16 lsBL[4096];
    const int t = threadIdx.x;
    int lin = blockIdx.x + gridDim.x * blockIdx.y;
    lin = xcd_swz(lin, gridDim.x * gridDim.y);
    const int row0 = (lin / gridDim.x) * 128, col0 = (lin % gridDim.x) * 128;
    const int z = blockIdx.z;
    const int fast = *flag;
    const size_t PSLAB = (size_t)BSc * 32;
    W += (size_t)z * wstride;
    Wraw += (size_t)z * wstride;
    C += (size_t)z * cstride;
    bias += (size_t)z * bstride;
    if (Ah2 && z == 1) {
        if (col0 != 0) return;                 // second GEMM has 128 cols only
        Ah = Ah2; Al = Al2;
        W = W2; Wraw = W2raw; ldw = ldw2;
        bias = bias2; C = C2; ldc = ldc2;
        Ch = nullptr; Cl = nullptr;
    }

    // A staging: chunk c (0..511) of the contiguous 8KB slab tile.
    const int c0 = t, c1 = 256 + t;
    const size_t abase = (size_t)row0 * 32;
    const u16* a0h = Ah + abase + (size_t)c0 * 8;
    const u16* a1h = Ah + abase + (size_t)c1 * 8;
    const u16* a0l = Al + abase + (size_t)c0 * 8;
    const u16* a1l = Al + abase + (size_t)c1 * 8;
    const unsigned d0 = (((unsigned)c0 & ~3u) | (((unsigned)c0 & 3u) ^ (((unsigned)c0 >> 3) & 3u))) * 8u;
    const unsigned d1 = (((unsigned)c1 & ~3u) | (((unsigned)c1 & 3u) ^ (((unsigned)c1 >> 3) & 3u))) * 8u;

    // B staging roles: 32k x 128 cols, thread=(k-pair, col-oct)
    const int bkp = t >> 4, bno = t & 15;
    const float* bp = W + (size_t)(bkp * 2) * ldw + col0 + bno * 8;
    const u16*  brp = Wraw + (size_t)(bkp * 2) * ldw + col0 + bno * 8;

    const int lane = t & 63;
    const int w = t >> 6;
    const int wr = (w >> 1) * 64, wc = (w & 1) * 64;
    const int kg = lane >> 4, lr = lane & 15;

    unsigned iaf[4];
#pragma unroll
    for (int mi = 0; mi < 4; ++mi) {
        int arow = wr + mi * 16 + lr;
        iaf[mi] = ((unsigned)(arow << 2) + ((unsigned)kg ^ (((unsigned)arow >> 1) & 3u))) * 8u;
    }

    f32x4 acc[4][4] = {};
    uint4 aU0h, aU1h, aU0l, aU1l;
    float4 bR[4];
    uint4 bU0, bU1;
    aU0h = *(const uint4*)a0h;
    aU1h = *(const uint4*)a1h;
    aU0l = *(const uint4*)a0l;
    aU1l = *(const uint4*)a1l;
    if (fast) {
        bU0 = *(const uint4*)brp;
        bU1 = *(const uint4*)(brp + ldw);
    } else {
        const float4* q0 = (const float4*)bp;
        const float4* q1 = (const float4*)(bp + ldw);
        bR[0] = q0[0]; bR[1] = q0[1]; bR[2] = q1[0]; bR[3] = q1[1];
    }

    for (int k0 = 0; k0 < K; k0 += 32) {
        if (k0) __syncthreads();
        // ---- A: 4 vector LDS writes (contiguous per wave, conflict-free) ----
        *(uint4*)&lsAH[d0] = aU0h;
        *(uint4*)&lsAH[d1] = aU1h;
        *(uint4*)&lsAL[d0] = aU0l;
        *(uint4*)&lsAL[d1] = aU1l;
        // ---- B: transpose-stage from registers ----
        {
            unsigned bb = (unsigned)(bkp >> 2) * 1024u + (unsigned)(bkp & 3) * 2u;
            if (fast) {
                const u16* e0 = (const u16*)&bU0;
                const u16* e1 = (const u16*)&bU1;
#pragma unroll
                for (int j = 0; j < 8; ++j) {
                    int slot = bno * 8 + (j ^ (bno & 7));   // bank-spread, bijective
                    *(unsigned*)&lsBH[bb + (unsigned)slot * 8u] = pk2(e0[j], e1[j]);
                }
            } else {
                float e0f[8], e1f[8];
                *(float4*)&e0f[0] = bR[0]; *(float4*)&e0f[4] = bR[1];
                *(float4*)&e1f[0] = bR[2]; *(float4*)&e1f[4] = bR[3];
#pragma unroll
                for (int j = 0; j < 8; ++j) {
                    int slot = bno * 8 + (j ^ (bno & 7));
                    u16 h0 = f2bf(e0f[j]), h1 = f2bf(e1f[j]);
                    *(unsigned*)&lsBH[bb + (unsigned)slot * 8u] = pk2(h0, h1);
                    u16 l0 = f2bf(e0f[j] - bf2f(h0));
                    u16 l1 = f2bf(e1f[j] - bf2f(h1));
                    *(unsigned*)&lsBL[bb + (unsigned)slot * 8u] = pk2(l0, l1);
                }
            }
        }
        __syncthreads();
        // prefetch next tile into regs (overlaps fragment reads + MFMA)
        if (k0 + 32 < K) {
            size_t soff = (size_t)((k0 >> 5) + 1) * PSLAB;
            aU0h = *(const uint4*)(a0h + soff);
            aU1h = *(const uint4*)(a1h + soff);
            aU0l = *(const uint4*)(a0l + soff);
            aU1l = *(const uint4*)(a1l + soff);
            if (fast) {
                bU0 = *(const uint4*)(brp + (size_t)(k0 + 32) * ldw);
                bU1 = *(const uint4*)(brp + (size_t)(k0 + 33) * ldw);
            } else {
                const float4* q0 = (const float4*)(bp + (size_t)(k0 + 32) * ldw);
                const float4* q1 = (const float4*)(bp + (size_t)(k0 + 33) * ldw);
                bR[0] = q0[0]; bR[1] = q0[1]; bR[2] = q1[0]; bR[3] = q1[1];
            }
        }
        // ---- fragments + MFMA ----
        bf16x8 aH[4], aL[4], bH[4], bL[4];
#pragma unroll
        for (int mi = 0; mi < 4; ++mi) {
            aH[mi] = *(const bf16x8*)&lsAH[iaf[mi]];
            aL[mi] = *(const bf16x8*)&lsAL[iaf[mi]];
        }
#pragma unroll
        for (int ni = 0; ni < 4; ++ni) {
            int c = wc + ni * 16 + lr;
            int slot = (c & ~7) | ((c ^ (c >> 3)) & 7);
            unsigned ib = (unsigned)kg * 1024u + (unsigned)slot * 8u;
            bH[ni] = *(const bf16x8*)&lsBH[ib];
            if (!fast) bL[ni] = *(const bf16x8*)&lsBL[ib];
        }
#pragma unroll
        for (int mi = 0; mi < 4; ++mi)
#pragma unroll
            for (int ni = 0; ni < 4; ++ni) {
                acc[mi][ni] = __builtin_amdgcn_mfma_f32_16x16x32_bf16(aH[mi], bH[ni], acc[mi][ni], 0, 0, 0);
                acc[mi][ni] = __builtin_amdgcn_mfma_f32_16x16x32_bf16(aL[mi], bH[ni], acc[mi][ni], 0, 0, 0);
            }
        if (!fast) {
#pragma unroll
            for (int mi = 0; mi < 4; ++mi)
#pragma unroll
                for (int ni = 0; ni < 4; ++ni)
                    acc[mi][ni] = __builtin_amdgcn_mfma_f32_16x16x32_bf16(aH[mi], bL[ni], acc[mi][ni], 0, 0, 0);
        }
    }
    // ---- epilogue: C/D layout col=lane&15, row=(lane>>4)*4+reg ----
    const int rb = row0 + wr + (lane >> 4) * 4;
#pragma unroll
    for (int ni = 0; ni < 4; ++ni) {
        int cc = col0 + wc + ni * 16 + lr;
        float bv = bias[cc];
#pragma unroll
        for (int mi = 0; mi < 4; ++mi) {
#pragma unroll
            for (int r2 = 0; r2 < 4; ++r2) {
                int rr = rb + mi * 16 + r2;
                float v = acc[mi][ni][r2] + bv;
                if (RELU) v = fmaxf(v, 0.f);
                if (C) C[(size_t)rr * ldc + cc] = v;
                if (Ch) {
                    size_t px = pidx(rr, cc);
                    u16 h = f2bf(v);
                    Ch[px] = h;
                    Cl[px] = f2bf(v - bf2f(h));
                }
            }
        }
    }
}

// ---------------- double-buffered small-M GEMM: 64x64 tile, 4x4 micro --------
template<int RELU>
__global__ __launch_bounds__(256) void k_dgemm(
    const float* __restrict__ A, int lda,
    const float* __restrict__ W, int ldw, int wcol0,
    const float* __restrict__ bias,
    float* __restrict__ C, int ldc,
    int M, int N, int K) {
    __shared__ float As[2][16][68];
    __shared__ float Bs[2][16][68];
    int t = threadIdx.x;
    int row0 = blockIdx.y * 64, col0 = blockIdx.x * 64;
    int ti = t >> 4, tj = t & 15;
    int arow = t >> 2, akq = (t & 3) << 2;
    int bk = t >> 4, bn = (t & 15) << 2;
    bool aok = (row0 + arow) < M;
    const float* ap = A + (size_t)(row0 + arow) * lda + akq;
    const float* bp = W + (size_t)bk * ldw + wcol0 + col0 + bn;
    float4 aR = aok ? *(const float4*)ap : make_float4(0.f, 0.f, 0.f, 0.f);
    float4 bR = *(const float4*)bp;
    As[0][akq + 0][arow] = aR.x;
    As[0][akq + 1][arow] = aR.y;
    As[0][akq + 2][arow] = aR.z;
    As[0][akq + 3][arow] = aR.w;
    *(float4*)&Bs[0][bk][bn] = bR;
    __syncthreads();
    int cur = 0;
    float acc[4][4] = {};
    for (int k0 = 0; k0 < K; k0 += 16) {
        bool more = (k0 + 16) < K;
        if (more) {
            aR = aok ? *(const float4*)(ap + k0 + 16) : make_float4(0.f, 0.f, 0.f, 0.f);
            bR = *(const float4*)(bp + (size_t)(k0 + 16) * ldw);
        }
#pragma unroll
        for (int k = 0; k < 16; ++k) {
            float a[4], b[4];
#pragma unroll
            for (int r = 0; r < 4; ++r) a[r] = As[cur][k][ti * 4 + r];
#pragma unroll
            for (int c = 0; c < 4; ++c) b[c] = Bs[cur][k][tj * 4 + c];
#pragma unroll
            for (int r = 0; r < 4; ++r)
#pragma unroll
                for (int c = 0; c < 4; ++c) acc[r][c] += a[r] * b[c];
        }
        if (more) {
            int nxt = cur ^ 1;
            As[nxt][akq + 0][arow] = aR.x;
            As[nxt][akq + 1][arow] = aR.y;
            As[nxt][akq + 2][arow] = aR.z;
            As[nxt][akq + 3][arow] = aR.w;
            *(float4*)&Bs[nxt][bk][bn] = bR;
            __syncthreads();
            cur = nxt;
        }
    }
    for (int r = 0; r < 4; ++r) {
        int rr = row0 + ti * 4 + r;
        if (rr >= M) continue;
        for (int c = 0; c < 4; ++c) {
            int cc = col0 + tj * 4 + c;
            float v = acc[r][c] + bias[cc];
            if (RELU) v = fmaxf(v, 0.f);
            C[(size_t)rr * ldc + cc] = v;
        }
    }
}

// ---------------- bbox-head GEMM (N=4) fused with inverse_sigmoid+sigmoid ----
__global__ __launch_bounds__(256) void k_gemm4(
    const float* __restrict__ A, const float* __restrict__ W,
    const float* __restrict__ bias, const float* __restrict__ rsel,
    float* __restrict__ oref, int M, int K) {
    int row = blockIdx.x * 64 + (threadIdx.x >> 2);
    int col = threadIdx.x & 3;
    if (row >= M) return;
    float acc = 0.f;
    const float* a = A + (size_t)row * K;
    for (int k = 0; k < K; ++k) acc += a[k] * W[k * 4 + col];
    float tmp = acc + bias[col];
    float r = rsel[(size_t)row * 4 + col];
    r = fminf(fmaxf(r, 1e-5f), 1.f - 1e-5f);
    float v = tmp + logf(r / (1.f - r));
    oref[(size_t)row * 4 + col] = 1.f / (1.f + __expf(-v));
}

// ---------------- LayerNorm (residual; optional plane outs; optional store) --
__global__ void k_ln(const float* __restrict__ a, const float* __restrict__ b,
                     const float* __restrict__ g, const float* __restrict__ be,
                     float* __restrict__ o,
                     u16* __restrict__ oh, u16* __restrict__ ol,
                     const float* __restrict__ padd, float* __restrict__ opadd,
                     u16* __restrict__ oph, u16* __restrict__ opl,
                     void* __restrict__ sdst, size_t soff,
                     const int* __restrict__ flag) {
    int row = blockIdx.x;
    int t = threadIdx.x;
    __shared__ float red[256];
    size_t ix = (size_t)row * 256 + t;
    float x = a[ix];
    if (b) x += b[ix];
    red[t] = x;
    __syncthreads();
    for (int s = 128; s > 0; s >>= 1) { if (t < s) red[t] += red[t + s]; __syncthreads(); }
    float mean = red[0] / 256.f;
    __syncthreads();
    float d = x - mean;
    red[t] = d * d;
    __syncthreads();
    for (int s = 128; s > 0; s >>= 1) { if (t < s) red[t] += red[t + s]; __syncthreads(); }
    float var = red[0] / 256.f;
    float y = d * rsqrtf(var + 1e-5f) * g[t] + be[t];
    o[ix] = y;
    if (oh) {
        size_t px = pidx(row, t);
        u16 h = f2bf(y);
        oh[px] = h;
        ol[px] = f2bf(y - bf2f(h));
    }
    if (padd) {
        float z = y + padd[ix];
        if (opadd) opadd[ix] = z;
        if (oph) {
            size_t px = pidx(row, t);
            u16 h = f2bf(z);
            oph[px] = h;
            opl[px] = f2bf(z - bf2f(h));
        }
    }
    if (sdst) {
        if (*flag) ((__hip_bfloat16*)sdst)[soff + ix] = __float2bfloat16(y);
        else       ((float*)sdst)[soff + ix] = y;
    }
}

// ---------------- ref windows ----------------
__global__ void k_refw(float* __restrict__ rw) {
    int s = blockIdx.x * 256 + threadIdx.x;
    if (s >= Sc) return;
    int start, HW;
    if (s < 4096)      { start = 0;    HW = 64; }
    else if (s < 5120) { start = 4096; HW = 32; }
    else if (s < 5376) { start = 5120; HW = 16; }
    else               { start = 5376; HW = 8;  }
    int loc = s - start;
    int i = loc / HW, j = loc % HW;
    rw[s * 4 + 0] = (j + 0.5f) / ((float)HW + 1e-6f);
    rw[s * 4 + 1] = (i + 0.5f) / ((float)HW + 1e-6f);
    rw[s * 4 + 2] = 4.0f / (float)HW;
    rw[s * 4 + 3] = 4.0f / (float)HW;
}

// ---------------- box attention sampling v4: wave/query, float4 channels ------
__global__ __launch_bounds__(256) void k_box_sample4(
    const float* __restrict__ v, const float* __restrict__ attn,
    const float* __restrict__ refw, int ref_bs,
    float* __restrict__ out, u16* __restrict__ outh, u16* __restrict__ outl,
    int N) {
    const int t = threadIdx.x;
    const int qi = t >> 6, lane = t & 63;
    const int blk = xcd_swz(blockIdx.x, gridDim.x);
    const int n = blk * 4 + qi;
    const int b = blockIdx.y;
    if (n >= N) return;                       // wave-uniform
    const float* arow = attn + ((size_t)b * N + n) * 128;
    float2 wl = *(const float2*)(arow + lane * 2);
    float m = fmaxf(wl.x, wl.y);
#pragma unroll
    for (int d2 = 1; d2 < 8; d2 <<= 1) m = fmaxf(m, __shfl_xor(m, d2, 8));
    float e0 = __expf(wl.x - m), e1 = __expf(wl.y - m);
    float s = e0 + e1;
#pragma unroll
    for (int d2 = 1; d2 < 8; d2 <<= 1) s += __shfl_xor(s, d2, 8);
    float inv = 1.f / s;
    e0 *= inv; e1 *= inv;

    const float* rw = refw + (size_t)ref_bs * b + (size_t)n * 4;
    float cx = rw[0], cy = rw[1], bw = rw[2], bh = rw[3];
    const float* vb = v + (size_t)b * Sc * 256 + lane * 4;
    float4 acc = make_float4(0.f, 0.f, 0.f, 0.f);
    int start = 0;
    const int HWs[4] = {64, 32, 16, 8};
#pragma unroll
    for (int l = 0; l < 4; ++l) {
        int HW = HWs[l];
#pragma unroll
        for (int p = 0; p < 4; ++p) {
            float gx = (p & 1) ? 0.25f : -0.25f;
            float gy = (p >> 1) ? 0.25f : -0.25f;
            float x = (cx + gx * bw) * (float)HW - 0.5f;
            float y = (cy + gy * bh) * (float)HW - 0.5f;
            float x0f = floorf(x), y0f = floorf(y);
            float wx = x - x0f, wy = y - y0f;
            int x0 = (int)x0f, y0 = (int)y0f;
            float4 smp = make_float4(0.f, 0.f, 0.f, 0.f);
            if (x0 >= 0 && x0 < HW && y0 >= 0 && y0 < HW) {
                float4 g4 = *(const float4*)(vb + (size_t)(start + y0 * HW + x0) * 256);
                float wgt = (1.f - wx) * (1.f - wy);
                smp.x += wgt * g4.x; smp.y += wgt * g4.y; smp.z += wgt * g4.z; smp.w += wgt * g4.w;
            }
            if (x0 + 1 >= 0 && x0 + 1 < HW && y0 >= 0 && y0 < HW) {
                float4 g4 = *(const float4*)(vb + (size_t)(start + y0 * HW + x0 + 1) * 256);
                float wgt = wx * (1.f - wy);
                smp.x += wgt * g4.x; smp.y += wgt * g4.y; smp.z += wgt * g4.z; smp.w += wgt * g4.w;
            }
            if (x0 >= 0 && x0 < HW && y0 + 1 >= 0 && y0 + 1 < HW) {
                float4 g4 = *(const float4*)(vb + (size_t)(start + (y0 + 1) * HW + x0) * 256);
                float wgt = (1.f - wx) * wy;
                smp.x += wgt * g4.x; smp.y += wgt * g4.y; smp.z += wgt * g4.z; smp.w += wgt * g4.w;
            }
            if (x0 + 1 >= 0 && x0 + 1 < HW && y0 + 1 >= 0 && y0 + 1 < HW) {
                float4 g4 = *(const float4*)(vb + (size_t)(start + (y0 + 1) * HW + x0 + 1) * 256);
                float wgt = wx * wy;
                smp.x += wgt * g4.x; smp.y += wgt * g4.y; smp.z += wgt * g4.z; smp.w += wgt * g4.w;
            }
            const int idx = l * 4 + p;
            float wsel = (idx & 1) ? e1 : e0;
            float wv = __shfl(wsel, (lane & ~7) | (idx >> 1), 64);
            acc.x += wv * smp.x; acc.y += wv * smp.y;
            acc.z += wv * smp.z; acc.w += wv * smp.w;
        }
        start += HW * HW;
    }
    if (out) {
        size_t obase = ((size_t)b * N + n) * 256 + lane * 4;
        *(float4*)(out + obase) = acc;
    }
    if (outh) {
        size_t px = pidx(b * N + n, lane * 4);
        ushort4 h, lo;
        h.x = f2bf(acc.x); h.y = f2bf(acc.y); h.z = f2bf(acc.z); h.w = f2bf(acc.w);
        lo.x = f2bf(acc.x - bf2f(h.x)); lo.y = f2bf(acc.y - bf2f(h.y));
        lo.z = f2bf(acc.z - bf2f(h.z)); lo.w = f2bf(acc.w - bf2f(h.w));
        *(ushort4*)(outh + px) = h;
        *(ushort4*)(outl + px) = lo;
    }
}

// ---------------- cls logits + valid mask ----------------
__global__ void k_cls(const float* __restrict__ x, const float* __restrict__ w,
                      const float* __restrict__ cb, const float* __restrict__ rw,
                      float* __restrict__ logits) {
    int row = blockIdx.x;
    int t = threadIdx.x;
    __shared__ float red[256];
    red[t] = x[(size_t)row * 256 + t] * w[t];
    __syncthreads();
    for (int s = 128; s > 0; s >>= 1) { if (t < s) red[t] += red[t + s]; __syncthreads(); }
    if (t == 0) {
        int s = row % Sc;
        float cx = rw[s * 4], cy = rw[s * 4 + 1];
        bool valid = (cx > 0.01f) && (cx < 0.99f) && (cy > 0.01f) && (cy < 0.99f);
        logits[row] = valid ? (red[0] + cb[0]) : -65504.0f;
    }
}

// ---------------- exact top-k: radix select (parallel suffix scan) + rank emit
__global__ void k_topk(const float* __restrict__ logits, int* __restrict__ idxout) {
    int b = blockIdx.x;
    int t = threadIdx.x;
    __shared__ unsigned keys[Sc];
    __shared__ int hist[256];
    __shared__ int suf[257];
    __shared__ unsigned sprefix;
    __shared__ int sR;
    __shared__ int cnt;
    __shared__ u64 cand[512];
    for (int i = t; i < Sc; i += 256) {
        union { float f; unsigned u; } x;
        x.f = logits[(size_t)b * Sc + i];
        unsigned u = x.u;
        keys[i] = (u & 0x80000000u) ? ~u : (u | 0x80000000u);
    }
    if (t == 0) { sprefix = 0; sR = NQc; suf[256] = 0; }
    __syncthreads();
    for (int shift = 24; shift >= 0; shift -= 8) {
        hist[t] = 0;
        __syncthreads();
        unsigned pref = sprefix;
        int R = sR;
        unsigned pmask = (shift == 24) ? 0u : (0xFFFFFFFFu << (shift + 8));
        for (int i = t; i < Sc; i += 256) {
            unsigned kk = keys[i];
            if ((kk & pmask) == (pref & pmask))
                atomicAdd(&hist[(kk >> shift) & 255], 1);
        }
        __syncthreads();
        suf[t] = hist[t];
        __syncthreads();
        for (int s2 = 1; s2 < 256; s2 <<= 1) {
            int vv = suf[t] + ((t + s2 < 256) ? suf[t + s2] : 0);
            __syncthreads();
            suf[t] = vv;
            __syncthreads();
        }
        if (suf[t] >= R && suf[t + 1] < R) {
            sR = R - suf[t + 1];
            sprefix = pref | ((unsigned)t << shift);
        }
        __syncthreads();
    }
    unsigned T = sprefix;
    if (t == 0) cnt = 0;
    __syncthreads();
    for (int i = t; i < Sc; i += 256) {
        unsigned kk = keys[i];
        if (kk >= T) {
            int slot = atomicAdd(&cnt, 1);
            if (slot < 512)
                cand[slot] = ~((((u64)kk) << 32) | (u64)(0xFFFFFFFFu - (unsigned)i));
        }
    }
    __syncthreads();
    int total = cnt < 512 ? cnt : 512;
    for (int i = t; i < 512; i += 256)
        if (i >= total) cand[i] = 0xFFFFFFFFFFFFFFFFull;
    __syncthreads();
    for (int i = t; i < 512; i += 256) {
        if (i >= total) continue;
        u64 mine = cand[i];
        int rank = 0;
        for (int j = 0; j < 512; ++j) rank += (cand[j] < mine) ? 1 : 0;
        if (rank < NQc) {
            u64 c = ~mine;
            idxout[b * NQc + rank] = (int)(0xFFFFFFFFu - (unsigned)(c & 0xFFFFFFFFull));
        }
    }
}

// ---------------- gather selected rows + ref windows ----------------
__global__ void k_gather(const float* __restrict__ x, const float* __restrict__ rw,
                         const int* __restrict__ idx, float* __restrict__ qemb,
                         float* __restrict__ refsel) {
    int q = blockIdx.x, b = blockIdx.y;
    int t = threadIdx.x;
    int id = idx[b * NQc + q];
    qemb[((size_t)b * NQc + q) * 256 + t] = x[((size_t)b * Sc + id) * 256 + t];
    if (t < 4) refsel[((size_t)b * NQc + q) * 4 + t] = rw[id * 4 + t];
}

// ---------------- sine positional embedding of boxes ----------------
__global__ void k_qpos(const float* __restrict__ outref, float* __restrict__ qpos) {
    int n = blockIdx.x, b = blockIdx.y;
    int t = threadIdx.x;
    const float* orf = outref + ((size_t)b * NQc + n) * 4;
    int c = t >> 7;
    int j = (t & 127) >> 1;
    int si = t & 1;
    float tj = powf(10000.f, (float)j / 64.f);
    float sc = 6.283185307179586f / tj;
    float v1 = orf[c] * sc;
    float v2 = orf[2 + c] * sc;
    float r = si ? (cosf(v1) + cosf(v2)) : (sinf(v1) + sinf(v2));
    qpos[((size_t)b * NQc + n) * 256 + t] = r;
}

// ---------------- MHA v3: thread=(query,head), 10-way key split (300=10x30) --
#define NSPL 10
#define SPLW 30
__global__ __launch_bounds__(256) void k_mha2(
    const float* __restrict__ qk, const float* __restrict__ v,
    float* __restrict__ opart, float* __restrict__ mlpart) {
    __shared__ float lsK[SPLW][256];
    __shared__ float lsV[SPLW][256];
    const int t = threadIdx.x;
    const int h = t >> 5, ql = t & 31;
    const int b = blockIdx.y, z = blockIdx.z;
    const int n = blockIdx.x * 32 + ql;
    const bool qok = n < NQc;
    const int kstart = z * SPLW;
    for (int f = t; f < SPLW * 64; f += 256) {
        int r = f >> 6, c4 = f & 63;
        int krow = kstart + r;
        float4 kv = *(const float4*)(qk + (size_t)(b * NQc + krow) * 512 + 256 + c4 * 4);
        float4 vv = *(const float4*)(v + (size_t)(b * NQc + krow) * 256 + c4 * 4);
        *(float4*)&lsK[r][c4 * 4] = kv;
        *(float4*)&lsV[r][c4 * 4] = vv;
    }
    __syncthreads();
    float q[32];
    {
        const float* qp = qk + (size_t)(b * NQc + (qok ? n : 0)) * 512 + h * 32;
#pragma unroll
        for (int j4 = 0; j4 < 8; ++j4) {
            float4 f = ((const float4*)qp)[j4];
            q[j4 * 4 + 0] = f.x; q[j4 * 4 + 1] = f.y;
            q[j4 * 4 + 2] = f.z; q[j4 * 4 + 3] = f.w;
        }
    }
    const float scale = 0.17677669529663688f;
    float s[SPLW];
#pragma unroll
    for (int kk = 0; kk < SPLW; ++kk) {
        float acc = 0.f;
        const float* kr = &lsK[kk][h * 32];
#pragma unroll
        for (int j4 = 0; j4 < 8; ++j4) {
            float4 kf = ((const float4*)kr)[j4];
            acc += q[j4*4+0]*kf.x + q[j4*4+1]*kf.y + q[j4*4+2]*kf.z + q[j4*4+3]*kf.w;
        }
        s[kk] = acc * scale;
    }
    float m = s[0];
#pragma unroll
    for (int kk = 1; kk < SPLW; ++kk) m = fmaxf(m, s[kk]);
    float o[32];
#pragma unroll
    for (int j = 0; j < 32; ++j) o[j] = 0.f;
    float l = 0.f;
#pragma unroll
    for (int kk = 0; kk < SPLW; ++kk) {
        float e = __expf(s[kk] - m);
        l += e;
        const float* vr = &lsV[kk][h * 32];
#pragma unroll
        for (int j4 = 0; j4 < 8; ++j4) {
            float4 vf = ((const float4*)vr)[j4];
            o[j4*4+0] += e * vf.x; o[j4*4+1] += e * vf.y;
            o[j4*4+2] += e * vf.z; o[j4*4+3] += e * vf.w;
        }
    }
    if (qok) {
        float* op = opart + ((size_t)z * BNQc + (size_t)b * NQc + n) * 256 + h * 32;
#pragma unroll
        for (int j4 = 0; j4 < 8; ++j4) {
            float4 f;
            f.x = o[j4*4+0]; f.y = o[j4*4+1]; f.z = o[j4*4+2]; f.w = o[j4*4+3];
            ((float4*)op)[j4] = f;
        }
        float* mlp = mlpart + ((size_t)z * BNQc + (size_t)b * NQc + n) * 16 + h * 2;
        mlp[0] = m; mlp[1] = l;
    }
}

__global__ void k_mha_comb(const float* __restrict__ opart, const float* __restrict__ mlpart,
                           float* __restrict__ out) {
    int row = blockIdx.x;           // b*NQc + n over BNQc
    int t = threadIdx.x;
    int h = t >> 5;
    float mm[NSPL], ll[NSPL];
    float M = -3.0e38f;
#pragma unroll
    for (int z = 0; z < NSPL; ++z) {
        mm[z] = mlpart[((size_t)z * BNQc + row) * 16 + h * 2];
        ll[z] = mlpart[((size_t)z * BNQc + row) * 16 + h * 2 + 1];
        M = fmaxf(M, mm[z]);
    }
    float denom = 0.f, osum = 0.f;
#pragma unroll
    for (int z = 0; z < NSPL; ++z) {
        float a = __expf(mm[z] - M);
        denom += ll[z] * a;
        osum += opart[((size_t)z * BNQc + row) * 256 + t] * a;
    }
    out[(size_t)row * 256 + t] = osum / denom;
}

// =====================================================================
extern "C" void kernel_launch(void* const* d_in, const int* in_sizes, int n_in,
                              void* d_out, int out_size, void* d_ws, size_t ws_size,
                              hipStream_t stream) {
    char* base = (char*)d_ws;
    size_t off = 0;
    auto allocB = [&](size_t bytes) {
        char* p = base + off;
        off = (off + bytes + 255) & ~(size_t)255;
        return p;
    };
    int* flag = (int*)allocB(16);
    auto allocF = [&](size_t n) { return (float*)allocB(n * 4); };
    auto allocH = [&](size_t n) { return (u16*)allocB(n * 2); };

    k_detect<<<1, 256, 0, stream>>>((const u16*)d_in[0], flag);

    // ---- one fused conversion of all 48 inputs ----
    CvtArgs ca;
    long acc = 0;
    int ninp = n_in < 48 ? n_in : 48;
    for (int i = 0; i < 48; ++i) {
        int idx2 = i < ninp ? i : ninp - 1;
        ca.in[i] = d_in[idx2];
        ca.n[i] = (i < ninp) ? in_sizes[i] : 0;
        ca.off[i] = acc;
        acc += ((long)ca.n[i] + 63) & ~63L;
    }
    ca.cnt = 48;
    ca.total = acc;
    // f32 copies of these segments are dead when inputs are bf16 (mgemm Wraw path)
    ca.skip = (1ull << 2) | (1ull << 4) | (1ull << 6) | (1ull << 8) |
              (1ull << 10) | (1ull << 20);
    float* cvtbase = allocF((size_t)acc);
    k_cvt_all8<<<(int)((acc / 8 + 255) / 256), 256, 0, stream>>>(ca, cvtbase, flag);
    float* F[48];
    for (int i = 0; i < 48; ++i) F[i] = cvtbase + ca.off[i];

    // ---- activation buffers ----
    const size_t BSD = (size_t)BSc * 256;
    float* enc    = F[0];                 // f32 activation (in-place)
    u16* encH  = allocH(BSD);  u16* encL  = allocH(BSD);
    u16* pbufH = allocH(BSD);  u16* pbufL = allocH(BSD);
    u16* tbufH = allocH(BSD);  u16* tbufL = allocH(BSD);
    u16* ffnhH = allocH((size_t)BSc * FFc);
    u16* ffnhL = allocH((size_t)BSc * FFc);
    float* vbuf   = allocF(BSD);               // encoder value buffer
    float* vbuf6  = allocF((size_t)NDc * BSD); // 6 decoder value buffers
    float* gout   = allocF(BSD);
    float* attnb  = allocF((size_t)BSc * 128);
    float* refw   = allocF(Sc * 4);
    float* logit  = allocF(BSc);
    int*   idx    = (int*)allocB(BNQc * 4);
    float* qemb   = allocF((size_t)BNQc * 256);
    float* rsel   = allocF(BNQc * 4);
    float* xbuf   = allocF((size_t)BNQc * 256);
    float* qposb  = allocF((size_t)BNQc * 256);
    float* dqk    = allocF((size_t)BNQc * 256);
    float* dqk512 = allocF((size_t)BNQc * 512);
    float* dv     = allocF((size_t)BNQc * 256);
    float* dt1    = allocF((size_t)BNQc * 256);
    float* dt2    = allocF((size_t)BNQc * 256);
    float* datt   = allocF((size_t)BNQc * 128);
    float* dffnh  = allocF((size_t)BNQc * FFc);
    float* h1f    = allocF((size_t)BNQc * 256);
    float* h2f    = allocF((size_t)BNQc * 256);
    float* oref   = allocF(BNQc * 4);
    float* opart  = allocF((size_t)NSPL * BNQc * 256);
    float* mlpart = allocF((size_t)NSPL * BNQc * 16);
    (void)ws_size; (void)out_size;

    auto MG = [&](int relu, const u16* Ah, const u16* Al, int widx, size_t woff, int ldw,
                  const float* bias, float* Cf, u16* Ch, u16* Cl, int ldc, int N, int K,
                  int nz, size_t wstride, int bstride, size_t cstride) {
        const float* Wf = F[widx] + woff;
        const u16* Wraw = (const u16*)d_in[widx] + woff;
        dim3 g(N / 128, BSc / 128, nz);
        if (relu) k_mgemm<1><<<g, 256, 0, stream>>>(Ah, Al, Wf, Wraw, ldw, wstride,
                                                    bias, bstride, Cf, cstride, Ch, Cl, ldc, K, flag,
                                                    nullptr, nullptr, nullptr, nullptr, 0, nullptr, nullptr, 0);
        else      k_mgemm<0><<<g, 256, 0, stream>>>(Ah, Al, Wf, Wraw, ldw, wstride,
                                                    bias, bstride, Cf, cstride, Ch, Cl, ldc, K, flag,
                                                    nullptr, nullptr, nullptr, nullptr, 0, nullptr, nullptr, 0);
    };
    // fused dual-GEMM: z=0 -> A1*W1(N=256)->C1 ; z=1 -> A2*W2(N=128)->C2
    auto MGF = [&](const u16* A1h, const u16* A1l, int w1, size_t w1off, const float* b1, float* C1,
                   const u16* A2h, const u16* A2l, int w2, size_t w2off, const float* b2, float* C2) {
        dim3 g(2, BSc / 128, 2);
        k_mgemm<0><<<g, 256, 0, stream>>>(A1h, A1l, F[w1] + w1off, (const u16*)d_in[w1] + w1off,
                                          256, 0, b1, 0, C1, 0, nullptr, nullptr, 256, 256, flag,
                                          A2h, A2l, F[w2] + w2off, (const u16*)d_in[w2] + w2off,
                                          128, b2, C2, 128);
    };
    auto DG = [&](int relu, const float* A, int lda, const float* W, int ldw, int wcol0,
                  const float* bias, float* C, int ldc, int M, int N, int K) {
        dim3 g(N / 64, (M + 63) / 64);
        if (relu) k_dgemm<1><<<g, 256, 0, stream>>>(A, lda, W, ldw, wcol0, bias, C, ldc, M, N, K);
        else      k_dgemm<0><<<g, 256, 0, stream>>>(A, lda, W, ldw, wcol0, bias, C, ldc, M, N, K);
    };

    const int nBSD = (int)BSD;
    k_refw<<<(Sc + 255) / 256, 256, 0, stream>>>(refw);
    // layer-0: enc planes + pbuf(=enc+pos) planes, fused
    k_addf2<<<(nBSD + 255) / 256, 256, 0, stream>>>(enc, F[1], encH, encL, pbufH, pbufL, nBSD);

    // ================= encoder =================
    for (int i = 0; i < NEc; ++i) {
        // fused: value projection (enc->vbuf, N=256) + attn logits (pbuf->attnb, N=128)
        MGF(encH, encL, 2, (size_t)i * 65536, F[3] + i * 256, vbuf,
            pbufH, pbufL, 4, (size_t)i * 32768, F[5] + i * 128, attnb);
        k_box_sample4<<<dim3((Sc + 3) / 4, Bc), 256, 0, stream>>>(vbuf, attnb, refw, 0,
                                                                  nullptr, tbufH, tbufL, Sc);
        MG(0, tbufH, tbufL, 6, (size_t)i * 65536, 256, F[7] + i * 256, gout, nullptr, nullptr,
           256, 256, 256, 1, 0, 0, 0);
        // LN1: y -> enc (f32) + enc planes (A of FFN1)
        k_ln<<<BSc, 256, 0, stream>>>(enc, gout, F[12] + i * 256, F[13] + i * 256,
                                      enc, encH, encL,
                                      nullptr, nullptr, nullptr, nullptr,
                                      nullptr, 0, flag);
        MG(1, encH, encL, 8, (size_t)i * 262144, 1024, F[9] + i * 1024,
           nullptr, ffnhH, ffnhL, 1024, 1024, 256, 1, 0, 0, 0);
        MG(0, ffnhH, ffnhL, 10, (size_t)i * 262144, 256, F[11] + i * 256,
           gout, nullptr, nullptr, 256, 256, 1024, 1, 0, 0, 0);
        // LN2: y -> enc + planes; pbuf planes (y+pos) for next layer
        k_ln<<<BSc, 256, 0, stream>>>(enc, gout, F[14] + i * 256, F[15] + i * 256,
                                      enc, encH, encL,
                                      (i < NEc - 1) ? F[1] : nullptr, nullptr,
                                      (i < NEc - 1) ? pbufH : nullptr,
                                      (i < NEc - 1) ? pbufL : nullptr,
                                      nullptr, 0, flag);
    }

    // ================= proposal selection =================
    k_cls<<<BSc, 256, 0, stream>>>(enc, F[36], F[37], refw, logit);
    k_topk<<<Bc, 256, 0, stream>>>(logit, idx);
    k_gather<<<dim3(NQc, Bc), 256, 0, stream>>>(enc, refw, idx, qemb, rsel);
    // batched: all 6 decoder V-projections in ONE dispatch (z = layer)
    MG(0, encH, encL, 20, 0, 256, F[21], vbuf6, nullptr, nullptr,
       256, 256, 256, NDc, 65536, 256, BSD);
    DG(0, qemb, 256, F[44], 256, 0, F[45], dt1, 256, BNQc, 256, 256);
    DG(1, qemb, 256, F[38], 256, 0, F[39], h1f, 256, BNQc, 256, 256);
    DG(1, h1f,  256, F[40], 256, 0, F[41], h2f, 256, BNQc, 256, 256);
    k_gemm4<<<(BNQc + 63) / 64, 256, 0, stream>>>(h2f, F[42], F[43], rsel, oref, BNQc, 256);
    k_qpos<<<dim3(NQc, Bc), 256, 0, stream>>>(oref, qposb);
    k_ln<<<BNQc, 256, 0, stream>>>(dt1, nullptr, F[46], F[47],
                                   xbuf, nullptr, nullptr,
                                   qposb, dqk, nullptr, nullptr,
                                   nullptr, 0, flag);   // tgt + first qk

    // ================= decoder =================
    const int nXD = BNQc * 256;
    for (int i = 0; i < NDc; ++i) {
        DG(0, dqk,  256, F[16] + (size_t)i * 196608, 768, 0,   F[17] + i * 768,       dqk512, 512, BNQc, 512, 256);
        DG(0, xbuf, 256, F[16] + (size_t)i * 196608, 768, 512, F[17] + i * 768 + 512, dv,     256, BNQc, 256, 256);
        k_mha2<<<dim3((NQc + 31) / 32, Bc, NSPL), 256, 0, stream>>>(dqk512, dv, opart, mlpart);
        k_mha_comb<<<BNQc, 256, 0, stream>>>(opart, mlpart, dt1);
        DG(0, dt1, 256, F[18] + (size_t)i * 65536, 256, 0, F[19] + i * 256, dt2, 256, BNQc, 256, 256);
        k_ln<<<BNQc, 256, 0, stream>>>(xbuf, dt2, F[30] + i * 256, F[31] + i * 256,
                                       xbuf, nullptr, nullptr,
                                       qposb, dqk, nullptr, nullptr,
                                       nullptr, 0, flag);
        DG(0, dqk, 256, F[22] + (size_t)i * 32768, 128, 0, F[23] + i * 128, datt, 128, BNQc, 128, 256);
        k_box_sample4<<<dim3((NQc + 3) / 4, Bc), 256, 0, stream>>>(vbuf6 + (size_t)i * BSD, datt,
                                                                   oref, NQc * 4,
                                                                   dt1, nullptr, nullptr, NQc);
        DG(0, dt1, 256, F[24] + (size_t)i * 65536, 256, 0, F[25] + i * 256, dt2, 256, BNQc, 256, 256);
        k_ln<<<BNQc, 256, 0, stream>>>(xbuf, dt2, F[32] + i * 256, F[33] + i * 256,
                                       xbuf, nullptr, nullptr,
                                       nullptr, nullptr, nullptr, nullptr,
                                       nullptr, 0, flag);
        DG(1, xbuf,  256,  F[26] + (size_t)i * 262144, 1024, 0, F[27] + i * 1024, dffnh, 1024, BNQc, 1024, 256);
        DG(0, dffnh, 1024, F[28] + (size_t)i * 262144, 256,  0, F[29] + i * 256,  dt2,   256,  BNQc, 256, 1024);
        k_ln<<<BNQc, 256, 0, stream>>>(xbuf, dt2, F[34] + i * 256, F[35] + i * 256,
                                       xbuf, nullptr, nullptr,
                                       (i < NDc - 1) ? qposb : nullptr,
                                       (i < NDc - 1) ? dqk : nullptr, nullptr, nullptr,
                                       d_out, (size_t)i * nXD, flag);
    }
}

// Round 16
// 2574.365 us; speedup vs baseline: 1.1373x; 1.0300x over previous
//
#include <hip/hip_runtime.h>
#include <hip/hip_bf16.h>
#include <math.h>

typedef unsigned short u16;
typedef unsigned int u32;
typedef unsigned long long u64;

#define Bc   2
#define NHc  8
#define Sc   5440
#define NQc  300
#define NEc  6
#define NDc  6
#define FFc  1024
#define BSc  (Bc*Sc)        // 10880
#define BNQc (Bc*NQc)       // 600

__device__ __forceinline__ float us2f(u16 u) {
    union { float f; unsigned v; } x; x.v = ((unsigned)u) << 16; return x.f;
}

// bf16 round-to-nearest-even (finite inputs)
__device__ __forceinline__ u16 f2bf(float f) {
    unsigned u = __float_as_uint(f);
    unsigned r = u + 0x7FFFu + ((u >> 16) & 1u);
    return (u16)(r >> 16);
}
__device__ __forceinline__ float bf2f(u16 u) { return us2f(u); }
__device__ __forceinline__ unsigned pk2(u16 a, u16 b) { return (unsigned)a | ((unsigned)b << 16); }

// k-tile-blocked plane layout: 32-k slabs, rows contiguous within a slab.
__device__ __forceinline__ size_t pidx(int row, int k) {
    return (size_t)(k >> 5) * ((size_t)BSc * 32) + ((size_t)row << 5) + (size_t)(k & 31);
}

// bijective XCD chunked swizzle (m204): contiguous ids -> same XCD's L2
__device__ __forceinline__ int xcd_swz(int orig, int nwg) {
    int xcd = orig & 7;
    int q = nwg >> 3, r = nwg & 7;
    int base = (xcd < r) ? xcd * (q + 1) : r * (q + 1) + (xcd - r) * q;
    return base + (orig >> 3);
}

using bf16x8 = __attribute__((ext_vector_type(8))) short;
using f32x4  = __attribute__((ext_vector_type(4))) float;

// ---------------- dtype detection (proven) ----------------
__global__ void k_detect(const u16* __restrict__ src, int* __restrict__ flag) {
    __shared__ int cnt;
    if (threadIdx.x == 0) cnt = 0;
    __syncthreads();
    u16 v = src[threadIdx.x];
    int e = (v >> 7) & 0xFF;
    int plaus = (e == 0) || (e >= 107 && e <= 131);
    atomicAdd(&cnt, plaus);
    __syncthreads();
    if (threadIdx.x == 0) *flag = (cnt >= 224) ? 1 : 0;
}

// ---------------- fused conversion of ALL inputs (8 elems/thread) ------------
// skip: bitmask of segments whose f32 copy is DEAD in fast(bf16) mode.
struct CvtArgs {
    const void* in[48];
    long off[48];
    int n[48];
    int cnt;
    long total;
    u64 skip;
};
__global__ void k_cvt_all8(CvtArgs args, float* __restrict__ out,
                           const int* __restrict__ flag) {
    long g = ((long)blockIdx.x * 256 + threadIdx.x) * 8;
    if (g >= args.total) return;
    int lo = 0, hi = args.cnt - 1;
    while (lo < hi) {
        int mid = (lo + hi + 1) >> 1;
        if (args.off[mid] <= g) lo = mid; else hi = mid - 1;
    }
    long local = g - args.off[lo];
    long n = (long)args.n[lo];
    float v[8];
#pragma unroll
    for (int j = 0; j < 8; ++j) v[j] = 0.f;
    if (*flag) {
        if ((args.skip >> lo) & 1) return;     // f32 copy never read in fast mode
        const u16* p = (const u16*)args.in[lo] + local;
        if (local + 8 <= n) {
            uint4 r = *(const uint4*)p;
            const u16* pu = (const u16*)&r;
#pragma unroll
            for (int j = 0; j < 8; ++j) v[j] = us2f(pu[j]);
        } else {
            for (int j = 0; j < 8; ++j)
                if (local + j < n) v[j] = us2f(p[j]);
        }
    } else {
        const float* p = (const float*)args.in[lo] + local;
        if (local + 8 <= n) {
            float4 a = ((const float4*)p)[0];
            float4 b = ((const float4*)p)[1];
            v[0] = a.x; v[1] = a.y; v[2] = a.z; v[3] = a.w;
            v[4] = b.x; v[5] = b.y; v[6] = b.z; v[7] = b.w;
        } else {
            for (int j = 0; j < 8; ++j)
                if (local + j < n) v[j] = p[j];
        }
    }
    float4 o0, o1;
    o0.x = v[0]; o0.y = v[1]; o0.z = v[2]; o0.w = v[3];
    o1.x = v[4]; o1.y = v[5]; o1.z = v[6]; o1.w = v[7];
    ((float4*)(out + g))[0] = o0;
    ((float4*)(out + g))[1] = o1;
}

// ---------------- fused prologue: enc planes + (enc+pos) planes --------------
__global__ void k_addf2(const float* __restrict__ a, const float* __restrict__ pos,
                        u16* __restrict__ ah, u16* __restrict__ al,
                        u16* __restrict__ ph, u16* __restrict__ pl, int n) {
    int i = blockIdx.x * 256 + threadIdx.x;
    if (i >= n) return;
    int row = i >> 8, k = i & 255;
    size_t px = pidx(row, k);
    float x = a[i];
    u16 h = f2bf(x);
    ah[px] = h;
    al[px] = f2bf(x - bf2f(h));
    float s = x + pos[i];
    u16 h2 = f2bf(s);
    ph[px] = h2;
    pl[px] = f2bf(s - bf2f(h2));
}

// ---------------- MFMA GEMM, blocked-plane-A, depth-1 prefetch ---------------
// C[ldc] = (Ah+Al)[BSc,K](bf16 planes, pidx layout) * W[K,N](ldw) + bias.
// M = BSc, N%128==0, K%32==0.
// blockIdx.z batching, two modes:
//   Ah2==null: z selects weight slice (W/Wraw += z*wstride, C += z*cstride).
//   Ah2!=null: z==1 runs a SECOND independent GEMM (Ah2*W2->C2, 128 cols:
//              only col-block 0 is valid; others exit).
template<int RELU>
__global__ __launch_bounds__(256) void k_mgemm(
    const u16* __restrict__ Ah, const u16* __restrict__ Al,
    const float* __restrict__ W, const u16* __restrict__ Wraw, int ldw,
    size_t wstride,
    const float* __restrict__ bias, int bstride,
    float* __restrict__ C, size_t cstride,
    u16* __restrict__ Ch, u16* __restrict__ Cl,
    int ldc, int K,
    const int* __restrict__ flag,
    const u16* __restrict__ Ah2, const u16* __restrict__ Al2,
    const float* __restrict__ W2, const u16* __restrict__ W2raw, int ldw2,
    const float* __restrict__ bias2, float* __restrict__ C2, int ldc2) {
    __shared__ __align__(16) u16 lsAH[4096];
    __shared__ __align__(16) u16 lsAL[4096];
    __shared__ __align__(16) u16 lsBH[4096];
    __shared__ __align__(16) u16 lsBL[4096];
    const int t = threadIdx.x;
    int lin = blockIdx.x + gridDim.x * blockIdx.y;
    lin = xcd_swz(lin, gridDim.x * gridDim.y);
    const int row0 = (lin / gridDim.x) * 128, col0 = (lin % gridDim.x) * 128;
    const int z = blockIdx.z;
    const int fast = *flag;
    const size_t PSLAB = (size_t)BSc * 32;
    W += (size_t)z * wstride;
    Wraw += (size_t)z * wstride;
    C += (size_t)z * cstride;
    bias += (size_t)z * bstride;
    if (Ah2 && z == 1) {
        if (col0 != 0) return;                 // second GEMM has 128 cols only
        Ah = Ah2; Al = Al2;
        W = W2; Wraw = W2raw; ldw = ldw2;
        bias = bias2; C = C2; ldc = ldc2;
        Ch = nullptr; Cl = nullptr;
    }

    // A staging: chunk c (0..511) of the contiguous 8KB slab tile.
    const int c0 = t, c1 = 256 + t;
    const size_t abase = (size_t)row0 * 32;
    const u16* a0h = Ah + abase + (size_t)c0 * 8;
    const u16* a1h = Ah + abase + (size_t)c1 * 8;
    const u16* a0l = Al + abase + (size_t)c0 * 8;
    const u16* a1l = Al + abase + (size_t)c1 * 8;
    const unsigned d0 = (((unsigned)c0 & ~3u) | (((unsigned)c0 & 3u) ^ (((unsigned)c0 >> 3) & 3u))) * 8u;
    const unsigned d1 = (((unsigned)c1 & ~3u) | (((unsigned)c1 & 3u) ^ (((unsigned)c1 >> 3) & 3u))) * 8u;

    // B staging roles: 32k x 128 cols, thread=(k-pair, col-oct)
    const int bkp = t >> 4, bno = t & 15;
    const float* bp = W + (size_t)(bkp * 2) * ldw + col0 + bno * 8;
    const u16*  brp = Wraw + (size_t)(bkp * 2) * ldw + col0 + bno * 8;

    const int lane = t & 63;
    const int w = t >> 6;
    const int wr = (w >> 1) * 64, wc = (w & 1) * 64;
    const int kg = lane >> 4, lr = lane & 15;

    unsigned iaf[4];
#pragma unroll
    for (int mi = 0; mi < 4; ++mi) {
        int arow = wr + mi * 16 + lr;
        iaf[mi] = ((unsigned)(arow << 2) + ((unsigned)kg ^ (((unsigned)arow >> 1) & 3u))) * 8u;
    }

    f32x4 acc[4][4] = {};
    uint4 aU0h, aU1h, aU0l, aU1l;
    float4 bR[4];
    uint4 bU0, bU1;
    aU0h = *(const uint4*)a0h;
    aU1h = *(const uint4*)a1h;
    aU0l = *(const uint4*)a0l;
    aU1l = *(const uint4*)a1l;
    if (fast) {
        bU0 = *(const uint4*)brp;
        bU1 = *(const uint4*)(brp + ldw);
    } else {
        const float4* q0 = (const float4*)bp;
        const float4* q1 = (const float4*)(bp + ldw);
        bR[0] = q0[0]; bR[1] = q0[1]; bR[2] = q1[0]; bR[3] = q1[1];
    }

    for (int k0 = 0; k0 < K; k0 += 32) {
        if (k0) __syncthreads();
        // ---- A: 4 vector LDS writes (contiguous per wave, conflict-free) ----
        *(uint4*)&lsAH[d0] = aU0h;
        *(uint4*)&lsAH[d1] = aU1h;
        *(uint4*)&lsAL[d0] = aU0l;
        *(uint4*)&lsAL[d1] = aU1l;
        // ---- B: transpose-stage from registers ----
        {
            unsigned bb = (unsigned)(bkp >> 2) * 1024u + (unsigned)(bkp & 3) * 2u;
            if (fast) {
                const u16* e0 = (const u16*)&bU0;
                const u16* e1 = (const u16*)&bU1;
#pragma unroll
                for (int j = 0; j < 8; ++j) {
                    int slot = bno * 8 + (j ^ (bno & 7));   // bank-spread, bijective
                    *(unsigned*)&lsBH[bb + (unsigned)slot * 8u] = pk2(e0[j], e1[j]);
                }
            } else {
                float e0f[8], e1f[8];
                *(float4*)&e0f[0] = bR[0]; *(float4*)&e0f[4] = bR[1];
                *(float4*)&e1f[0] = bR[2]; *(float4*)&e1f[4] = bR[3];
#pragma unroll
                for (int j = 0; j < 8; ++j) {
                    int slot = bno * 8 + (j ^ (bno & 7));
                    u16 h0 = f2bf(e0f[j]), h1 = f2bf(e1f[j]);
                    *(unsigned*)&lsBH[bb + (unsigned)slot * 8u] = pk2(h0, h1);
                    u16 l0 = f2bf(e0f[j] - bf2f(h0));
                    u16 l1 = f2bf(e1f[j] - bf2f(h1));
                    *(unsigned*)&lsBL[bb + (unsigned)slot * 8u] = pk2(l0, l1);
                }
            }
        }
        __syncthreads();
        // prefetch next tile into regs (overlaps fragment reads + MFMA)
        if (k0 + 32 < K) {
            size_t soff = (size_t)((k0 >> 5) + 1) * PSLAB;
            aU0h = *(const uint4*)(a0h + soff);
            aU1h = *(const uint4*)(a1h + soff);
            aU0l = *(const uint4*)(a0l + soff);
            aU1l = *(const uint4*)(a1l + soff);
            if (fast) {
                bU0 = *(const uint4*)(brp + (size_t)(k0 + 32) * ldw);
                bU1 = *(const uint4*)(brp + (size_t)(k0 + 33) * ldw);
            } else {
                const float4* q0 = (const float4*)(bp + (size_t)(k0 + 32) * ldw);
                const float4* q1 = (const float4*)(bp + (size_t)(k0 + 33) * ldw);
                bR[0] = q0[0]; bR[1] = q0[1]; bR[2] = q1[0]; bR[3] = q1[1];
            }
        }
        // ---- fragments + MFMA ----
        bf16x8 aH[4], aL[4], bH[4], bL[4];
#pragma unroll
        for (int mi = 0; mi < 4; ++mi) {
            aH[mi] = *(const bf16x8*)&lsAH[iaf[mi]];
            aL[mi] = *(const bf16x8*)&lsAL[iaf[mi]];
        }
#pragma unroll
        for (int ni = 0; ni < 4; ++ni) {
            int c = wc + ni * 16 + lr;
            int slot = (c & ~7) | ((c ^ (c >> 3)) & 7);
            unsigned ib = (unsigned)kg * 1024u + (unsigned)slot * 8u;
            bH[ni] = *(const bf16x8*)&lsBH[ib];
            if (!fast) bL[ni] = *(const bf16x8*)&lsBL[ib];
        }
#pragma unroll
        for (int mi = 0; mi < 4; ++mi)
#pragma unroll
            for (int ni = 0; ni < 4; ++ni) {
                acc[mi][ni] = __builtin_amdgcn_mfma_f32_16x16x32_bf16(aH[mi], bH[ni], acc[mi][ni], 0, 0, 0);
                acc[mi][ni] = __builtin_amdgcn_mfma_f32_16x16x32_bf16(aL[mi], bH[ni], acc[mi][ni], 0, 0, 0);
            }
        if (!fast) {
#pragma unroll
            for (int mi = 0; mi < 4; ++mi)
#pragma unroll
                for (int ni = 0; ni < 4; ++ni)
                    acc[mi][ni] = __builtin_amdgcn_mfma_f32_16x16x32_bf16(aH[mi], bL[ni], acc[mi][ni], 0, 0, 0);
        }
    }
    // ---- epilogue: C/D layout col=lane&15, row=(lane>>4)*4+reg ----
    const int rb = row0 + wr + (lane >> 4) * 4;
#pragma unroll
    for (int ni = 0; ni < 4; ++ni) {
        int cc = col0 + wc + ni * 16 + lr;
        float bv = bias[cc];
#pragma unroll
        for (int mi = 0; mi < 4; ++mi) {
#pragma unroll
            for (int r2 = 0; r2 < 4; ++r2) {
                int rr = rb + mi * 16 + r2;
                float v = acc[mi][ni][r2] + bv;
                if (RELU) v = fmaxf(v, 0.f);
                if (C) C[(size_t)rr * ldc + cc] = v;
                if (Ch) {
                    size_t px = pidx(rr, cc);
                    u16 h = f2bf(v);
                    Ch[px] = h;
                    Cl[px] = f2bf(v - bf2f(h));
                }
            }
        }
    }
}

// ---------------- double-buffered small-M GEMM: 64x64 tile, 4x4 micro --------
// Optional dual mode: A2!=null and blockIdx.z==1 runs a second independent
// GEMM (A2[ld a2] * W[wcol02..]+bias2 -> C2[ldc2], N2 cols; extra col-blocks
// exit). Same M/K/W as primary. Used for decoder qk/v projections.
template<int RELU>
__global__ __launch_bounds__(256) void k_dgemm(
    const float* __restrict__ A, int lda,
    const float* __restrict__ W, int ldw, int wcol0,
    const float* __restrict__ bias,
    float* __restrict__ C, int ldc,
    int M, int N, int K,
    const float* __restrict__ A2, int lda2, int wcol02,
    const float* __restrict__ bias2,
    float* __restrict__ C2, int ldc2, int N2) {
    __shared__ float As[2][16][68];
    __shared__ float Bs[2][16][68];
    int t = threadIdx.x;
    int row0 = blockIdx.y * 64, col0 = blockIdx.x * 64;
    if (A2 && blockIdx.z == 1) {
        if (col0 >= N2) return;
        A = A2; lda = lda2; wcol0 = wcol02;
        bias = bias2; C = C2; ldc = ldc2;
    }
    int ti = t >> 4, tj = t & 15;
    int arow = t >> 2, akq = (t & 3) << 2;
    int bk = t >> 4, bn = (t & 15) << 2;
    bool aok = (row0 + arow) < M;
    const float* ap = A + (size_t)(row0 + arow) * lda + akq;
    const float* bp = W + (size_t)bk * ldw + wcol0 + col0 + bn;
    float4 aR = aok ? *(const float4*)ap : make_float4(0.f, 0.f, 0.f, 0.f);
    float4 bR = *(const float4*)bp;
    As[0][akq + 0][arow] = aR.x;
    As[0][akq + 1][arow] = aR.y;
    As[0][akq + 2][arow] = aR.z;
    As[0][akq + 3][arow] = aR.w;
    *(float4*)&Bs[0][bk][bn] = bR;
    __syncthreads();
    int cur = 0;
    float acc[4][4] = {};
    for (int k0 = 0; k0 < K; k0 += 16) {
        bool more = (k0 + 16) < K;
        if (more) {
            aR = aok ? *(const float4*)(ap + k0 + 16) : make_float4(0.f, 0.f, 0.f, 0.f);
            bR = *(const float4*)(bp + (size_t)(k0 + 16) * ldw);
        }
#pragma unroll
        for (int k = 0; k < 16; ++k) {
            float a[4], b[4];
#pragma unroll
            for (int r = 0; r < 4; ++r) a[r] = As[cur][k][ti * 4 + r];
#pragma unroll
            for (int c = 0; c < 4; ++c) b[c] = Bs[cur][k][tj * 4 + c];
#pragma unroll
            for (int r = 0; r < 4; ++r)
#pragma unroll
                for (int c = 0; c < 4; ++c) acc[r][c] += a[r] * b[c];
        }
        if (more) {
            int nxt = cur ^ 1;
            As[nxt][akq + 0][arow] = aR.x;
            As[nxt][akq + 1][arow] = aR.y;
            As[nxt][akq + 2][arow] = aR.z;
            As[nxt][akq + 3][arow] = aR.w;
            *(float4*)&Bs[nxt][bk][bn] = bR;
            __syncthreads();
            cur = nxt;
        }
    }
    for (int r = 0; r < 4; ++r) {
        int rr = row0 + ti * 4 + r;
        if (rr >= M) continue;
        for (int c = 0; c < 4; ++c) {
            int cc = col0 + tj * 4 + c;
            float v = acc[r][c] + bias[cc];
            if (RELU) v = fmaxf(v, 0.f);
            C[(size_t)rr * ldc + cc] = v;
        }
    }
}

// ---------------- bbox-head GEMM (N=4) fused with inverse_sigmoid+sigmoid ----
__global__ __launch_bounds__(256) void k_gemm4(
    const float* __restrict__ A, const float* __restrict__ W,
    const float* __restrict__ bias, const float* __restrict__ rsel,
    float* __restrict__ oref, int M, int K) {
    int row = blockIdx.x * 64 + (threadIdx.x >> 2);
    int col = threadIdx.x & 3;
    if (row >= M) return;
    float acc = 0.f;
    const float* a = A + (size_t)row * K;
    for (int k = 0; k < K; ++k) acc += a[k] * W[k * 4 + col];
    float tmp = acc + bias[col];
    float r = rsel[(size_t)row * 4 + col];
    r = fminf(fmaxf(r, 1e-5f), 1.f - 1e-5f);
    float v = tmp + logf(r / (1.f - r));
    oref[(size_t)row * 4 + col] = 1.f / (1.f + __expf(-v));
}

// ---------------- LayerNorm (residual; optional plane outs; optional store) --
__global__ void k_ln(const float* __restrict__ a, const float* __restrict__ b,
                     const float* __restrict__ g, const float* __restrict__ be,
                     float* __restrict__ o,
                     u16* __restrict__ oh, u16* __restrict__ ol,
                     const float* __restrict__ padd, float* __restrict__ opadd,
                     u16* __restrict__ oph, u16* __restrict__ opl,
                     void* __restrict__ sdst, size_t soff,
                     const int* __restrict__ flag) {
    int row = blockIdx.x;
    int t = threadIdx.x;
    __shared__ float red[256];
    size_t ix = (size_t)row * 256 + t;
    float x = a[ix];
    if (b) x += b[ix];
    red[t] = x;
    __syncthreads();
    for (int s = 128; s > 0; s >>= 1) { if (t < s) red[t] += red[t + s]; __syncthreads(); }
    float mean = red[0] / 256.f;
    __syncthreads();
    float d = x - mean;
    red[t] = d * d;
    __syncthreads();
    for (int s = 128; s > 0; s >>= 1) { if (t < s) red[t] += red[t + s]; __syncthreads(); }
    float var = red[0] / 256.f;
    float y = d * rsqrtf(var + 1e-5f) * g[t] + be[t];
    o[ix] = y;
    if (oh) {
        size_t px = pidx(row, t);
        u16 h = f2bf(y);
        oh[px] = h;
        ol[px] = f2bf(y - bf2f(h));
    }
    if (padd) {
        float z = y + padd[ix];
        if (opadd) opadd[ix] = z;
        if (oph) {
            size_t px = pidx(row, t);
            u16 h = f2bf(z);
            oph[px] = h;
            opl[px] = f2bf(z - bf2f(h));
        }
    }
    if (sdst) {
        if (*flag) ((__hip_bfloat16*)sdst)[soff + ix] = __float2bfloat16(y);
        else       ((float*)sdst)[soff + ix] = y;
    }
}

// ---------------- ref windows ----------------
__global__ void k_refw(float* __restrict__ rw) {
    int s = blockIdx.x * 256 + threadIdx.x;
    if (s >= Sc) return;
    int start, HW;
    if (s < 4096)      { start = 0;    HW = 64; }
    else if (s < 5120) { start = 4096; HW = 32; }
    else if (s < 5376) { start = 5120; HW = 16; }
    else               { start = 5376; HW = 8;  }
    int loc = s - start;
    int i = loc / HW, j = loc % HW;
    rw[s * 4 + 0] = (j + 0.5f) / ((float)HW + 1e-6f);
    rw[s * 4 + 1] = (i + 0.5f) / ((float)HW + 1e-6f);
    rw[s * 4 + 2] = 4.0f / (float)HW;
    rw[s * 4 + 3] = 4.0f / (float)HW;
}

// ---------------- box attention sampling v4: wave/query, float4 channels ------
__global__ __launch_bounds__(256) void k_box_sample4(
    const float* __restrict__ v, const float* __restrict__ attn,
    const float* __restrict__ refw, int ref_bs,
    float* __restrict__ out, u16* __restrict__ outh, u16* __restrict__ outl,
    int N) {
    const int t = threadIdx.x;
    const int qi = t >> 6, lane = t & 63;
    const int blk = xcd_swz(blockIdx.x, gridDim.x);
    const int n = blk * 4 + qi;
    const int b = blockIdx.y;
    if (n >= N) return;                       // wave-uniform
    const float* arow = attn + ((size_t)b * N + n) * 128;
    float2 wl = *(const float2*)(arow + lane * 2);
    float m = fmaxf(wl.x, wl.y);
#pragma unroll
    for (int d2 = 1; d2 < 8; d2 <<= 1) m = fmaxf(m, __shfl_xor(m, d2, 8));
    float e0 = __expf(wl.x - m), e1 = __expf(wl.y - m);
    float s = e0 + e1;
#pragma unroll
    for (int d2 = 1; d2 < 8; d2 <<= 1) s += __shfl_xor(s, d2, 8);
    float inv = 1.f / s;
    e0 *= inv; e1 *= inv;

    const float* rw = refw + (size_t)ref_bs * b + (size_t)n * 4;
    float cx = rw[0], cy = rw[1], bw = rw[2], bh = rw[3];
    const float* vb = v + (size_t)b * Sc * 256 + lane * 4;
    float4 acc = make_float4(0.f, 0.f, 0.f, 0.f);
    int start = 0;
    const int HWs[4] = {64, 32, 16, 8};
#pragma unroll
    for (int l = 0; l < 4; ++l) {
        int HW = HWs[l];
#pragma unroll
        for (int p = 0; p < 4; ++p) {
            float gx = (p & 1) ? 0.25f : -0.25f;
            float gy = (p >> 1) ? 0.25f : -0.25f;
            float x = (cx + gx * bw) * (float)HW - 0.5f;
            float y = (cy + gy * bh) * (float)HW - 0.5f;
            float x0f = floorf(x), y0f = floorf(y);
            float wx = x - x0f, wy = y - y0f;
            int x0 = (int)x0f, y0 = (int)y0f;
            float4 smp = make_float4(0.f, 0.f, 0.f, 0.f);
            if (x0 >= 0 && x0 < HW && y0 >= 0 && y0 < HW) {
                float4 g4 = *(const float4*)(vb + (size_t)(start + y0 * HW + x0) * 256);
                float wgt = (1.f - wx) * (1.f - wy);
                smp.x += wgt * g4.x; smp.y += wgt * g4.y; smp.z += wgt * g4.z; smp.w += wgt * g4.w;
            }
            if (x0 + 1 >= 0 && x0 + 1 < HW && y0 >= 0 && y0 < HW) {
                float4 g4 = *(const float4*)(vb + (size_t)(start + y0 * HW + x0 + 1) * 256);
                float wgt = wx * (1.f - wy);
                smp.x += wgt * g4.x; smp.y += wgt * g4.y; smp.z += wgt * g4.z; smp.w += wgt * g4.w;
            }
            if (x0 >= 0 && x0 < HW && y0 + 1 >= 0 && y0 + 1 < HW) {
                float4 g4 = *(const float4*)(vb + (size_t)(start + (y0 + 1) * HW + x0) * 256);
                float wgt = (1.f - wx) * wy;
                smp.x += wgt * g4.x; smp.y += wgt * g4.y; smp.z += wgt * g4.z; smp.w += wgt * g4.w;
            }
            if (x0 + 1 >= 0 && x0 + 1 < HW && y0 + 1 >= 0 && y0 + 1 < HW) {
                float4 g4 = *(const float4*)(vb + (size_t)(start + (y0 + 1) * HW + x0 + 1) * 256);
                float wgt = wx * wy;
                smp.x += wgt * g4.x; smp.y += wgt * g4.y; smp.z += wgt * g4.z; smp.w += wgt * g4.w;
            }
            const int idx = l * 4 + p;
            float wsel = (idx & 1) ? e1 : e0;
            float wv = __shfl(wsel, (lane & ~7) | (idx >> 1), 64);
            acc.x += wv * smp.x; acc.y += wv * smp.y;
            acc.z += wv * smp.z; acc.w += wv * smp.w;
        }
        start += HW * HW;
    }
    if (out) {
        size_t obase = ((size_t)b * N + n) * 256 + lane * 4;
        *(float4*)(out + obase) = acc;
    }
    if (outh) {
        size_t px = pidx(b * N + n, lane * 4);
        ushort4 h, lo;
        h.x = f2bf(acc.x); h.y = f2bf(acc.y); h.z = f2bf(acc.z); h.w = f2bf(acc.w);
        lo.x = f2bf(acc.x - bf2f(h.x)); lo.y = f2bf(acc.y - bf2f(h.y));
        lo.z = f2bf(acc.z - bf2f(h.z)); lo.w = f2bf(acc.w - bf2f(h.w));
        *(ushort4*)(outh + px) = h;
        *(ushort4*)(outl + px) = lo;
    }
}

// ---------------- cls logits + valid mask ----------------
__global__ void k_cls(const float* __restrict__ x, const float* __restrict__ w,
                      const float* __restrict__ cb, const float* __restrict__ rw,
                      float* __restrict__ logits) {
    int row = blockIdx.x;
    int t = threadIdx.x;
    __shared__ float red[256];
    red[t] = x[(size_t)row * 256 + t] * w[t];
    __syncthreads();
    for (int s = 128; s > 0; s >>= 1) { if (t < s) red[t] += red[t + s]; __syncthreads(); }
    if (t == 0) {
        int s = row % Sc;
        float cx = rw[s * 4], cy = rw[s * 4 + 1];
        bool valid = (cx > 0.01f) && (cx < 0.99f) && (cy > 0.01f) && (cy < 0.99f);
        logits[row] = valid ? (red[0] + cb[0]) : -65504.0f;
    }
}

// ---------------- exact top-k: radix select (parallel suffix scan) + rank emit
__global__ void k_topk(const float* __restrict__ logits, int* __restrict__ idxout) {
    int b = blockIdx.x;
    int t = threadIdx.x;
    __shared__ unsigned keys[Sc];
    __shared__ int hist[256];
    __shared__ int suf[257];
    __shared__ unsigned sprefix;
    __shared__ int sR;
    __shared__ int cnt;
    __shared__ u64 cand[512];
    for (int i = t; i < Sc; i += 256) {
        union { float f; unsigned u; } x;
        x.f = logits[(size_t)b * Sc + i];
        unsigned u = x.u;
        keys[i] = (u & 0x80000000u) ? ~u : (u | 0x80000000u);
    }
    if (t == 0) { sprefix = 0; sR = NQc; suf[256] = 0; }
    __syncthreads();
    for (int shift = 24; shift >= 0; shift -= 8) {
        hist[t] = 0;
        __syncthreads();
        unsigned pref = sprefix;
        int R = sR;
        unsigned pmask = (shift == 24) ? 0u : (0xFFFFFFFFu << (shift + 8));
        for (int i = t; i < Sc; i += 256) {
            unsigned kk = keys[i];
            if ((kk & pmask) == (pref & pmask))
                atomicAdd(&hist[(kk >> shift) & 255], 1);
        }
        __syncthreads();
        suf[t] = hist[t];
        __syncthreads();
        for (int s2 = 1; s2 < 256; s2 <<= 1) {
            int vv = suf[t] + ((t + s2 < 256) ? suf[t + s2] : 0);
            __syncthreads();
            suf[t] = vv;
            __syncthreads();
        }
        if (suf[t] >= R && suf[t + 1] < R) {
            sR = R - suf[t + 1];
            sprefix = pref | ((unsigned)t << shift);
        }
        __syncthreads();
    }
    unsigned T = sprefix;
    if (t == 0) cnt = 0;
    __syncthreads();
    for (int i = t; i < Sc; i += 256) {
        unsigned kk = keys[i];
        if (kk >= T) {
            int slot = atomicAdd(&cnt, 1);
            if (slot < 512)
                cand[slot] = ~((((u64)kk) << 32) | (u64)(0xFFFFFFFFu - (unsigned)i));
        }
    }
    __syncthreads();
    int total = cnt < 512 ? cnt : 512;
    for (int i = t; i < 512; i += 256)
        if (i >= total) cand[i] = 0xFFFFFFFFFFFFFFFFull;
    __syncthreads();
    for (int i = t; i < 512; i += 256) {
        if (i >= total) continue;
        u64 mine = cand[i];
        int rank = 0;
        for (int j = 0; j < 512; ++j) rank += (cand[j] < mine) ? 1 : 0;
        if (rank < NQc) {
            u64 c = ~mine;
            idxout[b * NQc + rank] = (int)(0xFFFFFFFFu - (unsigned)(c & 0xFFFFFFFFull));
        }
    }
}

// ---------------- gather selected rows + ref windows ----------------
__global__ void k_gather(const float* __restrict__ x, const float* __restrict__ rw,
                         const int* __restrict__ idx, float* __restrict__ qemb,
                         float* __restrict__ refsel) {
    int q = blockIdx.x, b = blockIdx.y;
    int t = threadIdx.x;
    int id = idx[b * NQc + q];
    qemb[((size_t)b * NQc + q) * 256 + t] = x[((size_t)b * Sc + id) * 256 + t];
    if (t < 4) refsel[((size_t)b * NQc + q) * 4 + t] = rw[id * 4 + t];
}

// ---------------- sine positional embedding of boxes ----------------
__global__ void k_qpos(const float* __restrict__ outref, float* __restrict__ qpos) {
    int n = blockIdx.x, b = blockIdx.y;
    int t = threadIdx.x;
    const float* orf = outref + ((size_t)b * NQc + n) * 4;
    int c = t >> 7;
    int j = (t & 127) >> 1;
    int si = t & 1;
    float tj = powf(10000.f, (float)j / 64.f);
    float sc = 6.283185307179586f / tj;
    float v1 = orf[c] * sc;
    float v2 = orf[2 + c] * sc;
    float r = si ? (cosf(v1) + cosf(v2)) : (sinf(v1) + sinf(v2));
    qpos[((size_t)b * NQc + n) * 256 + t] = r;
}

// ---------------- MHA v3: thread=(query,head), 10-way key split (300=10x30) --
#define NSPL 10
#define SPLW 30
__global__ __launch_bounds__(256) void k_mha2(
    const float* __restrict__ qk, const float* __restrict__ v,
    float* __restrict__ opart, float* __restrict__ mlpart) {
    __shared__ float lsK[SPLW][256];
    __shared__ float lsV[SPLW][256];
    const int t = threadIdx.x;
    const int h = t >> 5, ql = t & 31;
    const int b = blockIdx.y, z = blockIdx.z;
    const int n = blockIdx.x * 32 + ql;
    const bool qok = n < NQc;
    const int kstart = z * SPLW;
    for (int f = t; f < SPLW * 64; f += 256) {
        int r = f >> 6, c4 = f & 63;
        int krow = kstart + r;
        float4 kv = *(const float4*)(qk + (size_t)(b * NQc + krow) * 512 + 256 + c4 * 4);
        float4 vv = *(const float4*)(v + (size_t)(b * NQc + krow) * 256 + c4 * 4);
        *(float4*)&lsK[r][c4 * 4] = kv;
        *(float4*)&lsV[r][c4 * 4] = vv;
    }
    __syncthreads();
    float q[32];
    {
        const float* qp = qk + (size_t)(b * NQc + (qok ? n : 0)) * 512 + h * 32;
#pragma unroll
        for (int j4 = 0; j4 < 8; ++j4) {
            float4 f = ((const float4*)qp)[j4];
            q[j4 * 4 + 0] = f.x; q[j4 * 4 + 1] = f.y;
            q[j4 * 4 + 2] = f.z; q[j4 * 4 + 3] = f.w;
        }
    }
    const float scale = 0.17677669529663688f;
    float s[SPLW];
#pragma unroll
    for (int kk = 0; kk < SPLW; ++kk) {
        float acc = 0.f;
        const float* kr = &lsK[kk][h * 32];
#pragma unroll
        for (int j4 = 0; j4 < 8; ++j4) {
            float4 kf = ((const float4*)kr)[j4];
            acc += q[j4*4+0]*kf.x + q[j4*4+1]*kf.y + q[j4*4+2]*kf.z + q[j4*4+3]*kf.w;
        }
        s[kk] = acc * scale;
    }
    float m = s[0];
#pragma unroll
    for (int kk = 1; kk < SPLW; ++kk) m = fmaxf(m, s[kk]);
    float o[32];
#pragma unroll
    for (int j = 0; j < 32; ++j) o[j] = 0.f;
    float l = 0.f;
#pragma unroll
    for (int kk = 0; kk < SPLW; ++kk) {
        float e = __expf(s[kk] - m);
        l += e;
        const float* vr = &lsV[kk][h * 32];
#pragma unroll
        for (int j4 = 0; j4 < 8; ++j4) {
            float4 vf = ((const float4*)vr)[j4];
            o[j4*4+0] += e * vf.x; o[j4*4+1] += e * vf.y;
            o[j4*4+2] += e * vf.z; o[j4*4+3] += e * vf.w;
        }
    }
    if (qok) {
        float* op = opart + ((size_t)z * BNQc + (size_t)b * NQc + n) * 256 + h * 32;
#pragma unroll
        for (int j4 = 0; j4 < 8; ++j4) {
            float4 f;
            f.x = o[j4*4+0]; f.y = o[j4*4+1]; f.z = o[j4*4+2]; f.w = o[j4*4+3];
            ((float4*)op)[j4] = f;
        }
        float* mlp = mlpart + ((size_t)z * BNQc + (size_t)b * NQc + n) * 16 + h * 2;
        mlp[0] = m; mlp[1] = l;
    }
}

__global__ void k_mha_comb(const float* __restrict__ opart, const float* __restrict__ mlpart,
                           float* __restrict__ out) {
    int row = blockIdx.x;           // b*NQc + n over BNQc
    int t = threadIdx.x;
    int h = t >> 5;
    float mm[NSPL], ll[NSPL];
    float M = -3.0e38f;
#pragma unroll
    for (int z = 0; z < NSPL; ++z) {
        mm[z] = mlpart[((size_t)z * BNQc + row) * 16 + h * 2];
        ll[z] = mlpart[((size_t)z * BNQc + row) * 16 + h * 2 + 1];
        M = fmaxf(M, mm[z]);
    }
    float denom = 0.f, osum = 0.f;
#pragma unroll
    for (int z = 0; z < NSPL; ++z) {
        float a = __expf(mm[z] - M);
        denom += ll[z] * a;
        osum += opart[((size_t)z * BNQc + row) * 256 + t] * a;
    }
    out[(size_t)row * 256 + t] = osum / denom;
}

// =====================================================================
extern "C" void kernel_launch(void* const* d_in, const int* in_sizes, int n_in,
                              void* d_out, int out_size, void* d_ws, size_t ws_size,
                              hipStream_t stream) {
    char* base = (char*)d_ws;
    size_t off = 0;
    auto allocB = [&](size_t bytes) {
        char* p = base + off;
        off = (off + bytes + 255) & ~(size_t)255;
        return p;
    };
    int* flag = (int*)allocB(16);
    auto allocF = [&](size_t n) { return (float*)allocB(n * 4); };
    auto allocH = [&](size_t n) { return (u16*)allocB(n * 2); };

    k_detect<<<1, 256, 0, stream>>>((const u16*)d_in[0], flag);

    // ---- one fused conversion of all 48 inputs ----
    CvtArgs ca;
    long acc = 0;
    int ninp = n_in < 48 ? n_in : 48;
    for (int i = 0; i < 48; ++i) {
        int idx2 = i < ninp ? i : ninp - 1;
        ca.in[i] = d_in[idx2];
        ca.n[i] = (i < ninp) ? in_sizes[i] : 0;
        ca.off[i] = acc;
        acc += ((long)ca.n[i] + 63) & ~63L;
    }
    ca.cnt = 48;
    ca.total = acc;
    // f32 copies of these segments are dead when inputs are bf16 (mgemm Wraw path)
    ca.skip = (1ull << 2) | (1ull << 4) | (1ull << 6) | (1ull << 8) |
              (1ull << 10) | (1ull << 20);
    float* cvtbase = allocF((size_t)acc);
    k_cvt_all8<<<(int)((acc / 8 + 255) / 256), 256, 0, stream>>>(ca, cvtbase, flag);
    float* F[48];
    for (int i = 0; i < 48; ++i) F[i] = cvtbase + ca.off[i];

    // ---- activation buffers ----
    const size_t BSD = (size_t)BSc * 256;
    float* enc    = F[0];                 // f32 activation (in-place)
    u16* encH  = allocH(BSD);  u16* encL  = allocH(BSD);
    u16* pbufH = allocH(BSD);  u16* pbufL = allocH(BSD);
    u16* tbufH = allocH(BSD);  u16* tbufL = allocH(BSD);
    u16* ffnhH = allocH((size_t)BSc * FFc);
    u16* ffnhL = allocH((size_t)BSc * FFc);
    float* vbuf   = allocF(BSD);               // encoder value buffer
    float* vbuf6  = allocF((size_t)NDc * BSD); // 6 decoder value buffers
    float* gout   = allocF(BSD);
    float* attnb  = allocF((size_t)BSc * 128);
    float* refw   = allocF(Sc * 4);
    float* logit  = allocF(BSc);
    int*   idx    = (int*)allocB(BNQc * 4);
    float* qemb   = allocF((size_t)BNQc * 256);
    float* rsel   = allocF(BNQc * 4);
    float* xbuf   = allocF((size_t)BNQc * 256);
    float* qposb  = allocF((size_t)BNQc * 256);
    float* dqk    = allocF((size_t)BNQc * 256);
    float* dqk512 = allocF((size_t)BNQc * 512);
    float* dv     = allocF((size_t)BNQc * 256);
    float* dt1    = allocF((size_t)BNQc * 256);
    float* dt2    = allocF((size_t)BNQc * 256);
    float* datt   = allocF((size_t)BNQc * 128);
    float* dffnh  = allocF((size_t)BNQc * FFc);
    float* h1f    = allocF((size_t)BNQc * 256);
    float* h2f    = allocF((size_t)BNQc * 256);
    float* oref   = allocF(BNQc * 4);
    float* opart  = allocF((size_t)NSPL * BNQc * 256);
    float* mlpart = allocF((size_t)NSPL * BNQc * 16);
    (void)ws_size; (void)out_size;

    auto MG = [&](int relu, const u16* Ah, const u16* Al, int widx, size_t woff, int ldw,
                  const float* bias, float* Cf, u16* Ch, u16* Cl, int ldc, int N, int K,
                  int nz, size_t wstride, int bstride, size_t cstride) {
        const float* Wf = F[widx] + woff;
        const u16* Wraw = (const u16*)d_in[widx] + woff;
        dim3 g(N / 128, BSc / 128, nz);
        if (relu) k_mgemm<1><<<g, 256, 0, stream>>>(Ah, Al, Wf, Wraw, ldw, wstride,
                                                    bias, bstride, Cf, cstride, Ch, Cl, ldc, K, flag,
                                                    nullptr, nullptr, nullptr, nullptr, 0, nullptr, nullptr, 0);
        else      k_mgemm<0><<<g, 256, 0, stream>>>(Ah, Al, Wf, Wraw, ldw, wstride,
                                                    bias, bstride, Cf, cstride, Ch, Cl, ldc, K, flag,
                                                    nullptr, nullptr, nullptr, nullptr, 0, nullptr, nullptr, 0);
    };
    // fused dual-GEMM: z=0 -> A1*W1(N=256)->C1 ; z=1 -> A2*W2(N=128)->C2
    auto MGF = [&](const u16* A1h, const u16* A1l, int w1, size_t w1off, const float* b1, float* C1,
                   const u16* A2h, const u16* A2l, int w2, size_t w2off, const float* b2, float* C2) {
        dim3 g(2, BSc / 128, 2);
        k_mgemm<0><<<g, 256, 0, stream>>>(A1h, A1l, F[w1] + w1off, (const u16*)d_in[w1] + w1off,
                                          256, 0, b1, 0, C1, 0, nullptr, nullptr, 256, 256, flag,
                                          A2h, A2l, F[w2] + w2off, (const u16*)d_in[w2] + w2off,
                                          128, b2, C2, 128);
    };
    auto DG = [&](int relu, const float* A, int lda, const float* W, int ldw, int wcol0,
                  const float* bias, float* C, int ldc, int M, int N, int K) {
        dim3 g(N / 64, (M + 63) / 64);
        if (relu) k_dgemm<1><<<g, 256, 0, stream>>>(A, lda, W, ldw, wcol0, bias, C, ldc, M, N, K,
                                                    nullptr, 0, 0, nullptr, nullptr, 0, 0);
        else      k_dgemm<0><<<g, 256, 0, stream>>>(A, lda, W, ldw, wcol0, bias, C, ldc, M, N, K,
                                                    nullptr, 0, 0, nullptr, nullptr, 0, 0);
    };
    // fused dual small-GEMM: z=0 -> A1*W[0..N1)->C1 ; z=1 -> A2*W[wcol02..+N2)->C2
    auto DGF = [&](const float* A1, const float* W, int ldw, const float* b1, float* C1, int ldc1, int N1,
                   const float* A2, int wcol02, const float* b2, float* C2, int ldc2, int N2, int K) {
        dim3 g(N1 / 64, (BNQc + 63) / 64, 2);
        k_dgemm<0><<<g, 256, 0, stream>>>(A1, 256, W, ldw, 0, b1, C1, ldc1, BNQc, N1, K,
                                          A2, 256, wcol02, b2, C2, ldc2, N2);
    };

    const int nBSD = (int)BSD;
    k_refw<<<(Sc + 255) / 256, 256, 0, stream>>>(refw);
    // layer-0: enc planes + pbuf(=enc+pos) planes, fused
    k_addf2<<<(nBSD + 255) / 256, 256, 0, stream>>>(enc, F[1], encH, encL, pbufH, pbufL, nBSD);

    // ================= encoder =================
    for (int i = 0; i < NEc; ++i) {
        // fused: value projection (enc->vbuf, N=256) + attn logits (pbuf->attnb, N=128)
        MGF(encH, encL, 2, (size_t)i * 65536, F[3] + i * 256, vbuf,
            pbufH, pbufL, 4, (size_t)i * 32768, F[5] + i * 128, attnb);
        k_box_sample4<<<dim3((Sc + 3) / 4, Bc), 256, 0, stream>>>(vbuf, attnb, refw, 0,
                                                                  nullptr, tbufH, tbufL, Sc);
        MG(0, tbufH, tbufL, 6, (size_t)i * 65536, 256, F[7] + i * 256, gout, nullptr, nullptr,
           256, 256, 256, 1, 0, 0, 0);
        // LN1: y -> enc (f32) + enc planes (A of FFN1)
        k_ln<<<BSc, 256, 0, stream>>>(enc, gout, F[12] + i * 256, F[13] + i * 256,
                                      enc, encH, encL,
                                      nullptr, nullptr, nullptr, nullptr,
                                      nullptr, 0, flag);
        MG(1, encH, encL, 8, (size_t)i * 262144, 1024, F[9] + i * 1024,
           nullptr, ffnhH, ffnhL, 1024, 1024, 256, 1, 0, 0, 0);
        MG(0, ffnhH, ffnhL, 10, (size_t)i * 262144, 256, F[11] + i * 256,
           gout, nullptr, nullptr, 256, 256, 1024, 1, 0, 0, 0);
        // LN2: y -> enc + planes; pbuf planes (y+pos) for next layer
        k_ln<<<BSc, 256, 0, stream>>>(enc, gout, F[14] + i * 256, F[15] + i * 256,
                                      enc, encH, encL,
                                      (i < NEc - 1) ? F[1] : nullptr, nullptr,
                                      (i < NEc - 1) ? pbufH : nullptr,
                                      (i < NEc - 1) ? pbufL : nullptr,
                                      nullptr, 0, flag);
    }

    // ================= proposal selection =================
    k_cls<<<BSc, 256, 0, stream>>>(enc, F[36], F[37], refw, logit);
    k_topk<<<Bc, 256, 0, stream>>>(logit, idx);
    k_gather<<<dim3(NQc, Bc), 256, 0, stream>>>(enc, refw, idx, qemb, rsel);
    // batched: all 6 decoder V-projections in ONE dispatch (z = layer)
    MG(0, encH, encL, 20, 0, 256, F[21], vbuf6, nullptr, nullptr,
       256, 256, 256, NDc, 65536, 256, BSD);
    DG(0, qemb, 256, F[44], 256, 0, F[45], dt1, 256, BNQc, 256, 256);
    DG(1, qemb, 256, F[38], 256, 0, F[39], h1f, 256, BNQc, 256, 256);
    DG(1, h1f,  256, F[40], 256, 0, F[41], h2f, 256, BNQc, 256, 256);
    k_gemm4<<<(BNQc + 63) / 64, 256, 0, stream>>>(h2f, F[42], F[43], rsel, oref, BNQc, 256);
    k_qpos<<<dim3(NQc, Bc), 256, 0, stream>>>(oref, qposb);
    k_ln<<<BNQc, 256, 0, stream>>>(dt1, nullptr, F[46], F[47],
                                   xbuf, nullptr, nullptr,
                                   qposb, dqk, nullptr, nullptr,
                                   nullptr, 0, flag);   // tgt + first qk

    // ================= decoder =================
    const int nXD = BNQc * 256;
    for (int i = 0; i < NDc; ++i) {
        // fused: qk projection (dqk->dqk512, W cols 0..512) + v projection
        //        (xbuf->dv, W cols 512..768) in one dispatch
        DGF(dqk, F[16] + (size_t)i * 196608, 768, F[17] + i * 768, dqk512, 512, 512,
            xbuf, 512, F[17] + i * 768 + 512, dv, 256, 256, 256);
        k_mha2<<<dim3((NQc + 31) / 32, Bc, NSPL), 256, 0, stream>>>(dqk512, dv, opart, mlpart);
        k_mha_comb<<<BNQc, 256, 0, stream>>>(opart, mlpart, dt1);
        DG(0, dt1, 256, F[18] + (size_t)i * 65536, 256, 0, F[19] + i * 256, dt2, 256, BNQc, 256, 256);
        k_ln<<<BNQc, 256, 0, stream>>>(xbuf, dt2, F[30] + i * 256, F[31] + i * 256,
                                       xbuf, nullptr, nullptr,
                                       qposb, dqk, nullptr, nullptr,
                                       nullptr, 0, flag);
        DG(0, dqk, 256, F[22] + (size_t)i * 32768, 128, 0, F[23] + i * 128, datt, 128, BNQc, 128, 256);
        k_box_sample4<<<dim3((NQc + 3) / 4, Bc), 256, 0, stream>>>(vbuf6 + (size_t)i * BSD, datt,
                                                                   oref, NQc * 4,
                                                                   dt1, nullptr, nullptr, NQc);
        DG(0, dt1, 256, F[24] + (size_t)i * 65536, 256, 0, F[25] + i * 256, dt2, 256, BNQc, 256, 256);
        k_ln<<<BNQc, 256, 0, stream>>>(xbuf, dt2, F[32] + i * 256, F[33] + i * 256,
                                       xbuf, nullptr, nullptr,
                                       nullptr, nullptr, nullptr, nullptr,
                                       nullptr, 0, flag);
        DG(1, xbuf,  256,  F[26] + (size_t)i * 262144, 1024, 0, F[27] + i * 1024, dffnh, 1024, BNQc, 1024, 256);
        DG(0, dffnh, 1024, F[28] + (size_t)i * 262144, 256,  0, F[29] + i * 256,  dt2,   256,  BNQc, 256, 1024);
        k_ln<<<BNQc, 256, 0, stream>>>(xbuf, dt2, F[34] + i * 256, F[35] + i * 256,
                                       xbuf, nullptr, nullptr,
                                       (i < NDc - 1) ? qposb : nullptr,
                                       (i < NDc - 1) ? dqk : nullptr, nullptr, nullptr,
                                       d_out, (size_t)i * nXD, flag);
    }
}